// Round 14
// baseline (197.656 us; speedup 1.0000x reference)
//
#include <hip/hip_runtime.h>

// B=2, S=2048, H=1024, NH=16, HD=64. f32 in/out; bf16 intermediates + MFMA.
// MFMA 16x16x32 bf16 layouts (m89/m91):
//   A: lane holds A[m=lane&15][k=quad*8+j]   B: B[k=quad*8+j][n=lane&15]
//   C/D: lane reg r -> row=quad*4+r, col=lane&15
typedef __bf16 bf16;
typedef __bf16 bf16x4 __attribute__((ext_vector_type(4)));
typedef __bf16 bf16x8 __attribute__((ext_vector_type(8)));
typedef float floatx4 __attribute__((ext_vector_type(4)));

#define MFMA16(a, b, c) __builtin_amdgcn_mfma_f32_16x16x32_bf16(a, b, c, 0, 0, 0)

__device__ __forceinline__ void load_lds16(const void* g, void* l) {
    // async global->LDS DMA, 16B/lane; dest = wave-uniform base + lane*16
    __builtin_amdgcn_global_load_lds(
        (const __attribute__((address_space(1))) unsigned int*)g,
        (__attribute__((address_space(3))) unsigned int*)l, 16, 0, 0);
}

__device__ __forceinline__ bf16x8 scale8(bf16x8 a, float s) {
    bf16x8 o;
    #pragma unroll
    for (int i = 0; i < 8; i++) o[i] = (bf16)((float)a[i] * s);
    return o;
}

// counted-vmcnt barrier pair (T3+T4): loads stay in flight across barriers.
#define WAITV4_BAR()  do { asm volatile("s_waitcnt vmcnt(4)" ::: "memory"); \
                           __builtin_amdgcn_s_barrier();                    \
                           __builtin_amdgcn_sched_barrier(0); } while (0)
#define WAITV0_BAR()  do { asm volatile("s_waitcnt vmcnt(0)" ::: "memory"); \
                           __builtin_amdgcn_s_barrier();                    \
                           __builtin_amdgcn_sched_barrier(0); } while (0)
#define TRAIL_BAR()   do { __builtin_amdgcn_sched_barrier(0);               \
                           asm volatile("s_waitcnt lgkmcnt(0)" ::: "memory"); \
                           __builtin_amdgcn_s_barrier(); } while (0)

// ---------------------------------------------------------------------------
// cvt: x (4096 blk), Wq/Wk/Wv/Wo (1024 blk each) f32 -> bf16
// ---------------------------------------------------------------------------
__global__ __launch_bounds__(256) void cvt_all_kernel(
    const float* __restrict__ x, const float* __restrict__ wq,
    const float* __restrict__ wk, const float* __restrict__ wv,
    const float* __restrict__ wo,
    bf16* __restrict__ xb, bf16* __restrict__ wqb, bf16* __restrict__ wkb,
    bf16* __restrict__ wvb, bf16* __restrict__ wob)
{
    int bid = blockIdx.x;
    const float* src; bf16* dst; int off;
    if (bid < 4096)      { src = x;  dst = xb;  off = bid; }
    else if (bid < 5120) { src = wq; dst = wqb; off = bid - 4096; }
    else if (bid < 6144) { src = wk; dst = wkb; off = bid - 5120; }
    else if (bid < 7168) { src = wv; dst = wvb; off = bid - 6144; }
    else                 { src = wo; dst = wob; off = bid - 7168; }
    int idx = (off * 256 + threadIdx.x) * 4;
    float4 v = *(const float4*)&src[idx];
    bf16x4 o;
    o[0] = (bf16)v.x; o[1] = (bf16)v.y; o[2] = (bf16)v.z; o[3] = (bf16)v.w;
    *(bf16x4*)&dst[idx] = o;
}

__global__ __launch_bounds__(256) void cvt_kernel(const float* __restrict__ x,
                                                  bf16* __restrict__ xb) {
    int idx = (blockIdx.x * 256 + threadIdx.x) * 4;
    float4 v = *(const float4*)&x[idx];
    bf16x4 o;
    o[0] = (bf16)v.x; o[1] = (bf16)v.y; o[2] = (bf16)v.z; o[3] = (bf16)v.w;
    *(bf16x4*)&xb[idx] = o;
}

// ===========================================================================
// FAST GEMMs V3: 2-phase BK=32 ping-pong with COUNTED vmcnt (T3+T4) + T5.
// (unchanged from round 4 — verified fast)
// ===========================================================================

#define PREP_STAGE()                                                          \
    int u0 = w * 128 + lane;                                                  \
    int u1 = u0 + 64;                                                         \
    int r0_ = u0 >> 2, c0_ = ((u0 & 3) ^ ((r0_ >> 1) & 3)) * 8;               \
    int r1_ = u1 >> 2, c1_ = ((u1 & 3) ^ ((r1_ >> 1) & 3)) * 8;               \
    int du0 = w * 1024;                                                       \
    int du1 = du0 + 512;

#define STAGE_PF(Asrc, Bsrc, arow, brow, sbuf, kk0)                           \
    do {                                                                      \
        load_lds16(&Asrc[(size_t)((arow) + r0_) * 1024 + (kk0) + c0_],        \
                   &As[sbuf][0][0] + du0);                                    \
        load_lds16(&Asrc[(size_t)((arow) + r1_) * 1024 + (kk0) + c1_],        \
                   &As[sbuf][0][0] + du1);                                    \
        load_lds16(&Bsrc[(size_t)((brow) + r0_) * 1024 + (kk0) + c0_],        \
                   &Bs[sbuf][0][0] + du0);                                    \
        load_lds16(&Bsrc[(size_t)((brow) + r1_) * 1024 + (kk0) + c1_],        \
                   &Bs[sbuf][0][0] + du1);                                    \
    } while (0)

#define GEMM_CORE(Asrc, Bsrc, arow, brow)                                     \
    PREP_STAGE()                                                              \
    STAGE_PF(Asrc, Bsrc, arow, brow, 0, 0);                                   \
    _Pragma("unroll 2")                                                       \
    for (int s = 0; s < 32; s++) {                                            \
        int sb = s & 1;                                                       \
        if (s + 1 < 32) {                                                     \
            STAGE_PF(Asrc, Bsrc, arow, brow, sb ^ 1, (s + 1) * 32);           \
            WAITV4_BAR();                                                     \
        } else {                                                              \
            WAITV0_BAR();                                                     \
        }                                                                     \
        bf16x8 af[4], bfr[4];                                                 \
        _Pragma("unroll")                                                     \
        for (int mt = 0; mt < 4; mt++) {                                      \
            int row = wm + mt * 16 + l15;                                     \
            af[mt] = *(const bf16x8*)&As[sb][row][(quad ^ ((row >> 1) & 3)) * 8]; \
        }                                                                     \
        _Pragma("unroll")                                                     \
        for (int nt = 0; nt < 4; nt++) {                                      \
            int row = wn + nt * 16 + l15;                                     \
            bfr[nt] = *(const bf16x8*)&Bs[sb][row][(quad ^ ((row >> 1) & 3)) * 8]; \
        }                                                                     \
        __builtin_amdgcn_s_setprio(1);                                        \
        _Pragma("unroll")                                                     \
        for (int mt = 0; mt < 4; mt++)                                        \
            _Pragma("unroll")                                                 \
            for (int nt = 0; nt < 4; nt++)                                    \
                acc[mt][nt] = MFMA16(af[mt], bfr[nt], acc[mt][nt]);           \
        __builtin_amdgcn_s_setprio(0);                                        \
        TRAIL_BAR();                                                          \
    }

// ---------------------------------------------------------------------------
// QKV projection + bias + fused RoPE (q,k) + transposed V store.
// q_ws,k_ws: (B,NH,S,HD); vt_ws: (B,NH,HD,S). All-bf16 inputs.
// ---------------------------------------------------------------------------
__global__ __launch_bounds__(256) void gemm_qkv_fast(
    const bf16* __restrict__ xb,
    const bf16* __restrict__ Wq, const bf16* __restrict__ Wk,
    const bf16* __restrict__ Wv,
    const float* __restrict__ bq, const float* __restrict__ bk,
    const float* __restrict__ bv,
    bf16* __restrict__ q_ws, bf16* __restrict__ k_ws, bf16* __restrict__ vt_ws)
{
    int m0 = blockIdx.x * 128;
    int n0 = blockIdx.y * 128;
    int sec = n0 >> 10;
    int nw0 = n0 & 1023;
    const bf16* W     = (sec == 0) ? Wq : (sec == 1) ? Wk : Wv;
    const float* bias = (sec == 0) ? bq : (sec == 1) ? bk : bv;

    __shared__ bf16 As[2][128][32];
    __shared__ bf16 Bs[2][128][32];

    int tid = threadIdx.x;
    int lane = tid & 63, w = tid >> 6;
    int l15 = lane & 15, quad = lane >> 4;
    int wm = (w >> 1) * 64, wn = (w & 1) * 64;

    floatx4 acc[4][4];
    #pragma unroll
    for (int i = 0; i < 4; i++)
        #pragma unroll
        for (int j = 0; j < 4; j++) acc[i][j] = (floatx4){0.f, 0.f, 0.f, 0.f};

    GEMM_CORE(xb, W, m0, nw0)

    if (sec < 2) {
        bf16* outp = (sec == 0) ? q_ws : k_ws;
        float inv[2];
        inv[0] = __expf(-(float)l15 * (9.210340371976184f / 32.0f));
        inv[1] = __expf(-(float)(16 + l15) * (9.210340371976184f / 32.0f));
        #pragma unroll
        for (int mt = 0; mt < 4; mt++) {
            #pragma unroll
            for (int r = 0; r < 4; r++) {
                int m = m0 + wm + mt * 16 + quad * 4 + r;
                int bb = m >> 11, s = m & 2047;
                #pragma unroll
                for (int nt = 0; nt < 2; nt++) {
                    int nl1 = nw0 + wn + nt * 16 + l15;
                    int nl2 = nl1 + 32;
                    float x1 = acc[mt][nt][r] + bias[nl1];
                    float x2 = acc[mt][nt + 2][r] + bias[nl2];
                    float ang = (float)s * inv[nt];
                    float sn, cs;
                    __sincosf(ang, &sn, &cs);
                    int hh = nl1 >> 6, d = nl1 & 63;
                    size_t base = ((size_t)(bb * 16 + hh) * 2048 + s) * 64;
                    outp[base + d]      = (bf16)(x1 * cs - x2 * sn);
                    outp[base + d + 32] = (bf16)(x2 * cs + x1 * sn);
                }
            }
        }
    } else {
        #pragma unroll
        for (int mt = 0; mt < 4; mt++) {
            int mbase = m0 + wm + mt * 16 + quad * 4;
            int bb = mbase >> 11, s0 = mbase & 2047;
            #pragma unroll
            for (int nt = 0; nt < 4; nt++) {
                int nl = nw0 + wn + nt * 16 + l15;
                int hh = nl >> 6, d = nl & 63;
                bf16x4 pk;
                #pragma unroll
                for (int r = 0; r < 4; r++) pk[r] = (bf16)(acc[mt][nt][r] + bias[nl]);
                *(bf16x4*)&vt_ws[((size_t)(bb * 16 + hh) * 64 + d) * 2048 + s0] = pk;
            }
        }
    }
}

// ---------------------------------------------------------------------------
// Output projection (fast): out[m][n] = sum_k O[m][k]*Wo[n][k] + bo[n]
// ---------------------------------------------------------------------------
__global__ __launch_bounds__(256) void gemm_out_fast(
    const bf16* __restrict__ A, const bf16* __restrict__ W,
    const float* __restrict__ bias, float* __restrict__ out)
{
    int m0 = blockIdx.x * 128;
    int n0 = blockIdx.y * 128;

    __shared__ bf16 As[2][128][32];
    __shared__ bf16 Bs[2][128][32];

    int tid = threadIdx.x;
    int lane = tid & 63, w = tid >> 6;
    int l15 = lane & 15, quad = lane >> 4;
    int wm = (w >> 1) * 64, wn = (w & 1) * 64;

    floatx4 acc[4][4];
    #pragma unroll
    for (int i = 0; i < 4; i++)
        #pragma unroll
        for (int j = 0; j < 4; j++) acc[i][j] = (floatx4){0.f, 0.f, 0.f, 0.f};

    GEMM_CORE(A, W, m0, n0)

    #pragma unroll
    for (int mt = 0; mt < 4; mt++) {
        #pragma unroll
        for (int r = 0; r < 4; r++) {
            int m = m0 + wm + mt * 16 + quad * 4 + r;
            #pragma unroll
            for (int nt = 0; nt < 4; nt++) {
                int nl = n0 + wn + nt * 16 + l15;
                out[(size_t)m * 1024 + nl] = acc[mt][nt][r] + bias[nl];
            }
        }
    }
}

// ===========================================================================
// FALLBACK GEMMs (f32 W staged with in-flight cvt) — used if ws too small
// ===========================================================================
__global__ __launch_bounds__(256) void gemm_qkv_f32w(
    const bf16* __restrict__ xb,
    const float* __restrict__ Wq, const float* __restrict__ Wk,
    const float* __restrict__ Wv,
    const float* __restrict__ bq, const float* __restrict__ bk,
    const float* __restrict__ bv,
    bf16* __restrict__ q_ws, bf16* __restrict__ k_ws, bf16* __restrict__ vt_ws)
{
    int m0 = blockIdx.x * 128;
    int n0 = blockIdx.y * 128;
    int sec = n0 >> 10;
    int nw0 = n0 & 1023;
    const float* W    = (sec == 0) ? Wq : (sec == 1) ? Wk : Wv;
    const float* bias = (sec == 0) ? bq : (sec == 1) ? bk : bv;

    __shared__ bf16 As[128][72];
    __shared__ bf16 Bs[128][72];

    int tid = threadIdx.x;
    int lane = tid & 63, w = tid >> 6;
    int l15 = lane & 15, quad = lane >> 4;
    int wm = (w >> 1) * 64, wn = (w & 1) * 64;
    int sr = tid >> 1;
    int sk = (tid & 1) * 32;

    floatx4 acc[4][4];
    #pragma unroll
    for (int i = 0; i < 4; i++)
        #pragma unroll
        for (int j = 0; j < 4; j++) acc[i][j] = (floatx4){0.f, 0.f, 0.f, 0.f};

    for (int k0 = 0; k0 < 1024; k0 += 64) {
        __syncthreads();
        const bf16* ap = &xb[(size_t)(m0 + sr) * 1024 + k0 + sk];
        bf16x8 a0 = *(const bf16x8*)(ap);
        bf16x8 a1 = *(const bf16x8*)(ap + 8);
        bf16x8 a2 = *(const bf16x8*)(ap + 16);
        bf16x8 a3 = *(const bf16x8*)(ap + 24);
        const float* wp = &W[(size_t)(nw0 + sr) * 1024 + k0 + sk];
        bf16x8 bv_[4];
        #pragma unroll
        for (int c = 0; c < 4; c++) {
            float4 f0 = *(const float4*)(wp + c * 8);
            float4 f1 = *(const float4*)(wp + c * 8 + 4);
            bf16x8 t;
            t[0] = (bf16)f0.x; t[1] = (bf16)f0.y; t[2] = (bf16)f0.z; t[3] = (bf16)f0.w;
            t[4] = (bf16)f1.x; t[5] = (bf16)f1.y; t[6] = (bf16)f1.z; t[7] = (bf16)f1.w;
            bv_[c] = t;
        }
        *(bf16x8*)&As[sr][sk + 0]  = a0;
        *(bf16x8*)&As[sr][sk + 8]  = a1;
        *(bf16x8*)&As[sr][sk + 16] = a2;
        *(bf16x8*)&As[sr][sk + 24] = a3;
        #pragma unroll
        for (int c = 0; c < 4; c++) *(bf16x8*)&Bs[sr][sk + c * 8] = bv_[c];
        __syncthreads();
        #pragma unroll
        for (int kk = 0; kk < 64; kk += 32) {
            bf16x8 af[4], bfr[4];
            #pragma unroll
            for (int mt = 0; mt < 4; mt++)
                af[mt] = *(const bf16x8*)&As[wm + mt * 16 + l15][kk + quad * 8];
            #pragma unroll
            for (int nt = 0; nt < 4; nt++)
                bfr[nt] = *(const bf16x8*)&Bs[wn + nt * 16 + l15][kk + quad * 8];
            #pragma unroll
            for (int mt = 0; mt < 4; mt++)
                #pragma unroll
                for (int nt = 0; nt < 4; nt++)
                    acc[mt][nt] = MFMA16(af[mt], bfr[nt], acc[mt][nt]);
        }
    }

    if (sec < 2) {
        bf16* outp = (sec == 0) ? q_ws : k_ws;
        float inv[2];
        inv[0] = __expf(-(float)l15 * (9.210340371976184f / 32.0f));
        inv[1] = __expf(-(float)(16 + l15) * (9.210340371976184f / 32.0f));
        #pragma unroll
        for (int mt = 0; mt < 4; mt++) {
            #pragma unroll
            for (int r = 0; r < 4; r++) {
                int m = m0 + wm + mt * 16 + quad * 4 + r;
                int bb = m >> 11, s = m & 2047;
                #pragma unroll
                for (int nt = 0; nt < 2; nt++) {
                    int nl1 = nw0 + wn + nt * 16 + l15;
                    int nl2 = nl1 + 32;
                    float x1 = acc[mt][nt][r] + bias[nl1];
                    float x2 = acc[mt][nt + 2][r] + bias[nl2];
                    float ang = (float)s * inv[nt];
                    float sn, cs;
                    __sincosf(ang, &sn, &cs);
                    int hh = nl1 >> 6, d = nl1 & 63;
                    size_t base = ((size_t)(bb * 16 + hh) * 2048 + s) * 64;
                    outp[base + d]      = (bf16)(x1 * cs - x2 * sn);
                    outp[base + d + 32] = (bf16)(x2 * cs + x1 * sn);
                }
            }
        }
    } else {
        #pragma unroll
        for (int mt = 0; mt < 4; mt++) {
            int mbase = m0 + wm + mt * 16 + quad * 4;
            int bb = mbase >> 11, s0 = mbase & 2047;
            #pragma unroll
            for (int nt = 0; nt < 4; nt++) {
                int nl = nw0 + wn + nt * 16 + l15;
                int hh = nl >> 6, d = nl & 63;
                bf16x4 pk;
                #pragma unroll
                for (int r = 0; r < 4; r++) pk[r] = (bf16)(acc[mt][nt][r] + bias[nl]);
                *(bf16x4*)&vt_ws[((size_t)(bb * 16 + hh) * 64 + d) * 2048 + s0] = pk;
            }
        }
    }
}

__global__ __launch_bounds__(256) void gemm_out_f32w(
    const bf16* __restrict__ A, const float* __restrict__ W,
    const float* __restrict__ bias, float* __restrict__ out)
{
    int m0 = blockIdx.x * 128;
    int n0 = blockIdx.y * 128;

    __shared__ bf16 As[128][72];
    __shared__ bf16 Bs[128][72];

    int tid = threadIdx.x;
    int lane = tid & 63, w = tid >> 6;
    int l15 = lane & 15, quad = lane >> 4;
    int wm = (w >> 1) * 64, wn = (w & 1) * 64;
    int sr = tid >> 1;
    int sk = (tid & 1) * 32;

    floatx4 acc[4][4];
    #pragma unroll
    for (int i = 0; i < 4; i++)
        #pragma unroll
        for (int j = 0; j < 4; j++) acc[i][j] = (floatx4){0.f, 0.f, 0.f, 0.f};

    for (int k0 = 0; k0 < 1024; k0 += 64) {
        __syncthreads();
        const bf16* ap = &A[(size_t)(m0 + sr) * 1024 + k0 + sk];
        bf16x8 a0 = *(const bf16x8*)(ap);
        bf16x8 a1 = *(const bf16x8*)(ap + 8);
        bf16x8 a2 = *(const bf16x8*)(ap + 16);
        bf16x8 a3 = *(const bf16x8*)(ap + 24);
        const float* wp = &W[(size_t)(n0 + sr) * 1024 + k0 + sk];
        bf16x8 bv_[4];
        #pragma unroll
        for (int c = 0; c < 4; c++) {
            float4 f0 = *(const float4*)(wp + c * 8);
            float4 f1 = *(const float4*)(wp + c * 8 + 4);
            bf16x8 t;
            t[0] = (bf16)f0.x; t[1] = (bf16)f0.y; t[2] = (bf16)f0.z; t[3] = (bf16)f0.w;
            t[4] = (bf16)f1.x; t[5] = (bf16)f1.y; t[6] = (bf16)f1.z; t[7] = (bf16)f1.w;
            bv_[c] = t;
        }
        *(bf16x8*)&As[sr][sk + 0]  = a0;
        *(bf16x8*)&As[sr][sk + 8]  = a1;
        *(bf16x8*)&As[sr][sk + 16] = a2;
        *(bf16x8*)&As[sr][sk + 24] = a3;
        #pragma unroll
        for (int c = 0; c < 4; c++) *(bf16x8*)&Bs[sr][sk + c * 8] = bv_[c];
        __syncthreads();
        #pragma unroll
        for (int kk = 0; kk < 64; kk += 32) {
            bf16x8 af[4], bfr[4];
            #pragma unroll
            for (int mt = 0; mt < 4; mt++)
                af[mt] = *(const bf16x8*)&As[wm + mt * 16 + l15][kk + quad * 8];
            #pragma unroll
            for (int nt = 0; nt < 4; nt++)
                bfr[nt] = *(const bf16x8*)&Bs[wn + nt * 16 + l15][kk + quad * 8];
            #pragma unroll
            for (int mt = 0; mt < 4; mt++)
                #pragma unroll
                for (int nt = 0; nt < 4; nt++)
                    acc[mt][nt] = MFMA16(af[mt], bfr[nt], acc[mt][nt]);
        }
    }

    #pragma unroll
    for (int mt = 0; mt < 4; mt++) {
        #pragma unroll
        for (int r = 0; r < 4; r++) {
            int m = m0 + wm + mt * 16 + quad * 4 + r;
            #pragma unroll
            for (int nt = 0; nt < 4; nt++) {
                int nl = n0 + wn + nt * 16 + l15;
                out[(size_t)m * 1024 + nl] = acc[mt][nt][r] + bias[nl];
            }
        }
    }
}

// ---------------------------------------------------------------------------
// MFMA flash attention V14: 32 QUERIES/WAVE at 4 WAVES/BLOCK (QBLK=128).
// Round-13 falsified barrier-count theory (KVBLK=128 flat) -> time scales
// with issued work. Pipe arithmetic: V11 issues ~180 LDS-pipe cyc/wave-iter
// x8 waves x66 CU-iters ~ 95-100K cyc vs 111K total: the CU's single LDS
// pipe is ~90% saturated. Fix = raise arithmetic intensity per LDS read:
// each wave owns 32 queries (2 frags qs=0,1); K/V frags are query-
// independent so the same ds_reads feed 2x MFMAs; per-work LDS cycles drop
// ~40%. Unlike V9 (confounded), waves/CU do NOT drop: 4-wave blocks, LDS
// 48KB -> up to 3 blocks/CU. Grid 512 (16 qt x 32 bh), longest-first.
// V11-verified mechanics carried verbatim: staging map + counted vmcnt(4)
// ping-pong, 3-bit chunk-XOR swizzles (row&7 == l15&7), fixed-max softmax,
// ones-MFMA l (per query frag), unroll-2 static buffers, XCD pinning.
// LDS: Ks[2][64][64] 16KB + Vt[2][64][64] 16KB + Ps[4][32][64] 16KB = 48KB.
// ---------------------------------------------------------------------------
__global__ __launch_bounds__(256, 2) void attn_kernel(
    const bf16* __restrict__ q_ws, const bf16* __restrict__ k_ws,
    const bf16* __restrict__ vt_ws, bf16* __restrict__ o_ws)
{
    __shared__ bf16 Ks[2][64][64];   // [buf][key][d], chunk-swizzled
    __shared__ bf16 Vt[2][64][64];   // [buf][d][key], chunk-swizzled
    __shared__ bf16 Ps[4][32][64];   // per-wave P [q][key], chunk-XOR swizzled

    int tid = threadIdx.x;
    int w = tid >> 6, lane = tid & 63;
    int l15 = lane & 15, quad = lane >> 4;

    int bid = blockIdx.x;            // 0..511
    int g = bid & 31;                // bh; bid%8==g%8 -> same XCD per bh
    int qt = 15 - (bid >> 5);        // 128-query tile, longest-first
    int bb = g >> 4, h = g & 15;
    const bf16* qp = q_ws + (size_t)g * 2048 * 64;
    const bf16* kp = k_ws + (size_t)g * 2048 * 64;
    const bf16* vp = vt_ws + (size_t)g * 64 * 2048;
    int qrow = qt * 128 + w * 32;    // wave's 32 queries: qrow + qs*16 + l15

    // staging map (V11 verbatim): wave w stages segments {2w,2w+1} of K and V.
    int g0 = (w * 2) * 64 + lane;
    int g1 = g0 + 64;
    int r0 = g0 >> 3, c0 = (g0 & 7) ^ (r0 & 7);
    int r1 = g1 >> 3, c1 = (g1 & 7) ^ (r1 & 7);
    int o0 = (w * 2) * 512;          // bf16 offset of wave's segment 0
    int o1 = o0 + 512;

    const float SCL = 0.125f * 1.4426950408889634f;   // (1/sqrt(HD))*log2(e)
    const float MFIX = 20.0f;        // fixed exp2-domain shift (folded in C-init)
    int lx7 = l15 & 7;               // swizzle key (== row&7 for all frag rows)

    bf16x8 ones8;
    #pragma unroll
    for (int i = 0; i < 8; i++) ones8[i] = (bf16)1.0f;

    // Q B-frags for 2 query sub-blocks, pre-scaled
    bf16x8 qf[2][2];
    #pragma unroll
    for (int qs = 0; qs < 2; qs++) {
        const bf16* qr = &qp[(size_t)(qrow + qs * 16 + l15) * 64];
        qf[qs][0] = scale8(*(const bf16x8*)&qr[quad * 8], SCL);
        qf[qs][1] = scale8(*(const bf16x8*)&qr[32 + quad * 8], SCL);
    }

    floatx4 lacc[2];
    floatx4 acc[4][2];
    #pragma unroll
    for (int qs = 0; qs < 2; qs++) {
        lacc[qs] = (floatx4){0.f, 0.f, 0.f, 0.f};
        #pragma unroll
        for (int nt = 0; nt < 4; nt++) acc[nt][qs] = (floatx4){0.f, 0.f, 0.f, 0.f};
    }

    int nkt = 2 * qt + 2;            // 64-key tiles covering keys 0..qt*128+127

    // running stage-source pointers (advance: K +4096 elems, V +64/tile)
    const bf16* kst0 = kp + (size_t)r0 * 64 + c0 * 8;
    const bf16* kst1 = kp + (size_t)r1 * 64 + c1 * 8;
    const bf16* vst0 = vp + (size_t)r0 * 2048 + c0 * 8;
    const bf16* vst1 = vp + (size_t)r1 * 2048 + c1 * 8;

    // prologue: stage kt=0 into buf 0
    load_lds16(kst0, &Ks[0][0][0] + o0);
    load_lds16(kst1, &Ks[0][0][0] + o1);
    load_lds16(vst0, &Vt[0][0][0] + o0);
    load_lds16(vst1, &Vt[0][0][0] + o1);
    kst0 += 4096; kst1 += 4096; vst0 += 64; vst1 += 64;

    #pragma unroll 2
    for (int kt = 0; kt < nkt; kt++) {
        int buf = kt & 1;            // compile-time per unrolled copy
        // issue prefetch kt+1 into buf^1, then counted publish of buf
        if (kt + 1 < nkt) {
            load_lds16(kst0, &Ks[buf ^ 1][0][0] + o0);
            load_lds16(kst1, &Ks[buf ^ 1][0][0] + o1);
            load_lds16(vst0, &Vt[buf ^ 1][0][0] + o0);
            load_lds16(vst1, &Vt[buf ^ 1][0][0] + o1);
            kst0 += 4096; kst1 += 4096; vst0 += 64; vst1 += 64;
            WAITV4_BAR();
        } else {
            WAITV0_BAR();
        }

        int kt0 = kt * 64;

        // S^T = K * Q^T : K frags read ONCE, reused for both query frags.
        floatx4 st[2][4];            // [qs][kb]
        __builtin_amdgcn_s_setprio(1);
        #pragma unroll
        for (int kb = 0; kb < 4; kb++) {
            int row = kb * 16 + l15;
            bf16x8 a0 = *(const bf16x8*)&Ks[buf][row][(quad ^ lx7) * 8];
            bf16x8 a1 = *(const bf16x8*)&Ks[buf][row][((quad + 4) ^ lx7) * 8];
            #pragma unroll
            for (int qs = 0; qs < 2; qs++) {
                floatx4 z = {-MFIX, -MFIX, -MFIX, -MFIX};
                z = MFMA16(a0, qf[qs][0], z);
                z = MFMA16(a1, qf[qs][1], z);
                st[qs][kb] = z;
            }
        }
        __builtin_amdgcn_s_setprio(0);
        if (kt0 + 63 > qrow) {       // tile reaches past wave's min query
            #pragma unroll
            for (int qs = 0; qs < 2; qs++) {
                int q = qrow + qs * 16 + l15;
                #pragma unroll
                for (int kb = 0; kb < 4; kb++)
                    #pragma unroll
                    for (int rr = 0; rr < 4; rr++) {
                        int key = kt0 + kb * 16 + quad * 4 + rr;
                        if (key > q) st[qs][kb][rr] = -1e30f;
                    }
            }
        }

        // fixed-max softmax; Ps write at chunk-XOR swizzled column
        #pragma unroll
        for (int qs = 0; qs < 2; qs++)
            #pragma unroll
            for (int kb = 0; kb < 4; kb++) {
                bf16x4 pk;
                #pragma unroll
                for (int rr = 0; rr < 4; rr++)
                    pk[rr] = (bf16)exp2f(st[qs][kb][rr]);
                int ch = kb * 2 + (quad >> 1);
                *(bf16x4*)&Ps[w][qs * 16 + l15][((ch ^ lx7) << 3) + ((quad & 1) << 2)] = pk;
            }

        // O^T += V^T * P^T : V frags read ONCE, reused for both query frags;
        // l via ones-MFMA per query frag.
        bf16x8 pb[2][2];
        #pragma unroll
        for (int qs = 0; qs < 2; qs++) {
            pb[qs][0] = *(const bf16x8*)&Ps[w][qs * 16 + l15][(quad ^ lx7) << 3];
            pb[qs][1] = *(const bf16x8*)&Ps[w][qs * 16 + l15][((quad + 4) ^ lx7) << 3];
        }
        __builtin_amdgcn_s_setprio(1);
        #pragma unroll
        for (int nt = 0; nt < 4; nt++) {
            int row = nt * 16 + l15;
            bf16x8 v0 = *(const bf16x8*)&Vt[buf][row][(quad ^ lx7) * 8];
            bf16x8 v1 = *(const bf16x8*)&Vt[buf][row][((quad + 4) ^ lx7) * 8];
            #pragma unroll
            for (int qs = 0; qs < 2; qs++) {
                acc[nt][qs] = MFMA16(v0, pb[qs][0], acc[nt][qs]);
                acc[nt][qs] = MFMA16(v1, pb[qs][1], acc[nt][qs]);
            }
        }
        #pragma unroll
        for (int qs = 0; qs < 2; qs++) {
            lacc[qs] = MFMA16(ones8, pb[qs][0], lacc[qs]);
            lacc[qs] = MFMA16(ones8, pb[qs][1], lacc[qs]);
        }
        __builtin_amdgcn_s_setprio(0);

        TRAIL_BAR();
    }

    // lacc rows all hold the per-query (l15) sum: no cross-lane reduce.
    #pragma unroll
    for (int qs = 0; qs < 2; qs++) {
        float inv = 1.f / lacc[qs][0];
        int s = qrow + qs * 16 + l15;
        #pragma unroll
        for (int nt = 0; nt < 4; nt++) {
            bf16x4 pk;
            #pragma unroll
            for (int rr = 0; rr < 4; rr++) pk[rr] = (bf16)(acc[nt][qs][rr] * inv);
            *(bf16x4*)&o_ws[((size_t)(bb * 2048 + s)) * 1024 + h * 64 + nt * 16 + quad * 4] = pk;
        }
    }
}

// ---------------------------------------------------------------------------
extern "C" void kernel_launch(void* const* d_in, const int* in_sizes, int n_in,
                              void* d_out, int out_size, void* d_ws, size_t ws_size,
                              hipStream_t stream) {
    const float* x  = (const float*)d_in[0];
    const float* Wq = (const float*)d_in[1];
    const float* bq = (const float*)d_in[2];
    const float* Wk = (const float*)d_in[3];
    const float* bk = (const float*)d_in[4];
    const float* Wv = (const float*)d_in[5];
    const float* bv = (const float*)d_in[6];
    const float* Wo = (const float*)d_in[7];
    const float* bo = (const float*)d_in[8];
    float* out = (float*)d_out;

    const size_t NELEM = (size_t)2 * 2048 * 1024;   // 4,194,304
    const size_t WELEM = (size_t)1024 * 1024;
    bf16* xb    = (bf16*)d_ws;          // 8MB; reused as o_ws after qkv
    bf16* q_ws  = xb + NELEM;
    bf16* k_ws  = q_ws + NELEM;
    bf16* vt_ws = k_ws + NELEM;         // (B,NH,HD,S)
    bf16* o_ws  = xb;
    bf16* wqb   = vt_ws + NELEM;        // +2MB each
    bf16* wkb   = wqb + WELEM;
    bf16* wvb   = wkb + WELEM;
    bf16* wob   = wvb + WELEM;          // ends at 40MB

    bool fast = ws_size >= (size_t)40 * 1024 * 1024;   // constant across calls

    if (fast) {
        cvt_all_kernel<<<8192, 256, 0, stream>>>(x, Wq, Wk, Wv, Wo,
                                                 xb, wqb, wkb, wvb, wob);
        gemm_qkv_fast<<<dim3(32, 24), 256, 0, stream>>>(
            xb, wqb, wkb, wvb, bq, bk, bv, q_ws, k_ws, vt_ws);
        attn_kernel<<<512, 256, 0, stream>>>(q_ws, k_ws, vt_ws, o_ws);
        gemm_out_fast<<<dim3(32, 8), 256, 0, stream>>>(o_ws, wob, bo, out);
    } else {
        cvt_kernel<<<4096, 256, 0, stream>>>(x, xb);
        gemm_qkv_f32w<<<dim3(32, 24), 256, 0, stream>>>(
            xb, Wq, Wk, Wv, bq, bk, bv, q_ws, k_ws, vt_ws);
        attn_kernel<<<512, 256, 0, stream>>>(q_ws, k_ws, vt_ws, o_ws);
        gemm_out_f32w<<<dim3(32, 8), 256, 0, stream>>>(o_ws, Wo, bo, out);
    }
}

// Round 15
// 193.688 us; speedup vs baseline: 1.0205x; 1.0205x over previous
//
#include <hip/hip_runtime.h>

// B=2, S=2048, H=1024, NH=16, HD=64. f32 in/out; bf16 intermediates + MFMA.
// MFMA 16x16x32 bf16 layouts (m89/m91):
//   A: lane holds A[m=lane&15][k=quad*8+j]   B: B[k=quad*8+j][n=lane&15]
//   C/D: lane reg r -> row=quad*4+r, col=lane&15
typedef __bf16 bf16;
typedef __bf16 bf16x4 __attribute__((ext_vector_type(4)));
typedef __bf16 bf16x8 __attribute__((ext_vector_type(8)));
typedef float floatx4 __attribute__((ext_vector_type(4)));

#define MFMA16(a, b, c) __builtin_amdgcn_mfma_f32_16x16x32_bf16(a, b, c, 0, 0, 0)

__device__ __forceinline__ void load_lds16(const void* g, void* l) {
    // async global->LDS DMA, 16B/lane; dest = wave-uniform base + lane*16
    __builtin_amdgcn_global_load_lds(
        (const __attribute__((address_space(1))) unsigned int*)g,
        (__attribute__((address_space(3))) unsigned int*)l, 16, 0, 0);
}

__device__ __forceinline__ bf16x8 scale8(bf16x8 a, float s) {
    bf16x8 o;
    #pragma unroll
    for (int i = 0; i < 8; i++) o[i] = (bf16)((float)a[i] * s);
    return o;
}

// counted-vmcnt barrier pair (T3+T4): loads stay in flight across barriers.
#define WAITV8_BAR()  do { asm volatile("s_waitcnt vmcnt(8)" ::: "memory"); \
                           __builtin_amdgcn_s_barrier();                    \
                           __builtin_amdgcn_sched_barrier(0); } while (0)
#define WAITV4_BAR()  do { asm volatile("s_waitcnt vmcnt(4)" ::: "memory"); \
                           __builtin_amdgcn_s_barrier();                    \
                           __builtin_amdgcn_sched_barrier(0); } while (0)
#define WAITV0_BAR()  do { asm volatile("s_waitcnt vmcnt(0)" ::: "memory"); \
                           __builtin_amdgcn_s_barrier();                    \
                           __builtin_amdgcn_sched_barrier(0); } while (0)
#define TRAIL_BAR()   do { __builtin_amdgcn_sched_barrier(0);               \
                           asm volatile("s_waitcnt lgkmcnt(0)" ::: "memory"); \
                           __builtin_amdgcn_s_barrier(); } while (0)

// ---------------------------------------------------------------------------
// cvt: x (4096 blk), Wq/Wk/Wv/Wo (1024 blk each) f32 -> bf16
// ---------------------------------------------------------------------------
__global__ __launch_bounds__(256) void cvt_all_kernel(
    const float* __restrict__ x, const float* __restrict__ wq,
    const float* __restrict__ wk, const float* __restrict__ wv,
    const float* __restrict__ wo,
    bf16* __restrict__ xb, bf16* __restrict__ wqb, bf16* __restrict__ wkb,
    bf16* __restrict__ wvb, bf16* __restrict__ wob)
{
    int bid = blockIdx.x;
    const float* src; bf16* dst; int off;
    if (bid < 4096)      { src = x;  dst = xb;  off = bid; }
    else if (bid < 5120) { src = wq; dst = wqb; off = bid - 4096; }
    else if (bid < 6144) { src = wk; dst = wkb; off = bid - 5120; }
    else if (bid < 7168) { src = wv; dst = wvb; off = bid - 6144; }
    else                 { src = wo; dst = wob; off = bid - 7168; }
    int idx = (off * 256 + threadIdx.x) * 4;
    float4 v = *(const float4*)&src[idx];
    bf16x4 o;
    o[0] = (bf16)v.x; o[1] = (bf16)v.y; o[2] = (bf16)v.z; o[3] = (bf16)v.w;
    *(bf16x4*)&dst[idx] = o;
}

__global__ __launch_bounds__(256) void cvt_kernel(const float* __restrict__ x,
                                                  bf16* __restrict__ xb) {
    int idx = (blockIdx.x * 256 + threadIdx.x) * 4;
    float4 v = *(const float4*)&x[idx];
    bf16x4 o;
    o[0] = (bf16)v.x; o[1] = (bf16)v.y; o[2] = (bf16)v.z; o[3] = (bf16)v.w;
    *(bf16x4*)&xb[idx] = o;
}

// ===========================================================================
// FAST GEMMs V4: BK=32 TRIPLE-buffer, prefetch depth 2 (T4 generalized;
// m218 steady state = multiple tiles in flight, never 1).
// Prologue stages tiles 0,1. Iter s: issue tile s+2 -> s_waitcnt vmcnt(8)
// (8 newer loads in flight; oldest tile guaranteed done) -> bare barrier ->
// ds_read + 16 MFMA -> lgkmcnt(0) + bare barrier. Each load gets TWO compute
// phases to cover L2 latency. Tail: vmcnt(4), vmcnt(0).
// Buffer reuse safe: iter s+1 stages into buf (s+3)%3 == s%3, fenced by
// iter s's trailing barrier.
// LDS: As[3][128][32] + Bs[3][128][32] = 48KB -> 3 blocks/CU (144<=160KB).
// ===========================================================================

#define PREP_STAGE()                                                          \
    int u0 = w * 128 + lane;                                                  \
    int u1 = u0 + 64;                                                         \
    int r0_ = u0 >> 2, c0_ = ((u0 & 3) ^ ((r0_ >> 1) & 3)) * 8;               \
    int r1_ = u1 >> 2, c1_ = ((u1 & 3) ^ ((r1_ >> 1) & 3)) * 8;               \
    int du0 = w * 1024;                                                       \
    int du1 = du0 + 512;

#define STAGE_PF(Asrc, Bsrc, arow, brow, sbuf, kk0)                           \
    do {                                                                      \
        load_lds16(&Asrc[(size_t)((arow) + r0_) * 1024 + (kk0) + c0_],        \
                   &As[sbuf][0][0] + du0);                                    \
        load_lds16(&Asrc[(size_t)((arow) + r1_) * 1024 + (kk0) + c1_],        \
                   &As[sbuf][0][0] + du1);                                    \
        load_lds16(&Bsrc[(size_t)((brow) + r0_) * 1024 + (kk0) + c0_],        \
                   &Bs[sbuf][0][0] + du0);                                    \
        load_lds16(&Bsrc[(size_t)((brow) + r1_) * 1024 + (kk0) + c1_],        \
                   &Bs[sbuf][0][0] + du1);                                    \
    } while (0)

#define GEMM_CORE(Asrc, Bsrc, arow, brow)                                     \
    PREP_STAGE()                                                              \
    STAGE_PF(Asrc, Bsrc, arow, brow, 0, 0);                                   \
    STAGE_PF(Asrc, Bsrc, arow, brow, 1, 32);                                  \
    _Pragma("unroll 3")                                                       \
    for (int s = 0; s < 32; s++) {                                            \
        int sb = s % 3;                                                       \
        if (s + 2 < 32) {                                                     \
            STAGE_PF(Asrc, Bsrc, arow, brow, (s + 2) % 3, (s + 2) * 32);      \
            WAITV8_BAR();                                                     \
        } else if (s + 1 < 32) {                                              \
            WAITV4_BAR();                                                     \
        } else {                                                              \
            WAITV0_BAR();                                                     \
        }                                                                     \
        bf16x8 af[4], bfr[4];                                                 \
        _Pragma("unroll")                                                     \
        for (int mt = 0; mt < 4; mt++) {                                      \
            int row = wm + mt * 16 + l15;                                     \
            af[mt] = *(const bf16x8*)&As[sb][row][(quad ^ ((row >> 1) & 3)) * 8]; \
        }                                                                     \
        _Pragma("unroll")                                                     \
        for (int nt = 0; nt < 4; nt++) {                                      \
            int row = wn + nt * 16 + l15;                                     \
            bfr[nt] = *(const bf16x8*)&Bs[sb][row][(quad ^ ((row >> 1) & 3)) * 8]; \
        }                                                                     \
        __builtin_amdgcn_s_setprio(1);                                        \
        _Pragma("unroll")                                                     \
        for (int mt = 0; mt < 4; mt++)                                        \
            _Pragma("unroll")                                                 \
            for (int nt = 0; nt < 4; nt++)                                    \
                acc[mt][nt] = MFMA16(af[mt], bfr[nt], acc[mt][nt]);           \
        __builtin_amdgcn_s_setprio(0);                                        \
        TRAIL_BAR();                                                          \
    }

// ---------------------------------------------------------------------------
// QKV projection + bias + fused RoPE (q,k) + transposed V store.
// q_ws,k_ws: (B,NH,S,HD); vt_ws: (B,NH,HD,S). All-bf16 inputs.
// ---------------------------------------------------------------------------
__global__ __launch_bounds__(256) void gemm_qkv_fast(
    const bf16* __restrict__ xb,
    const bf16* __restrict__ Wq, const bf16* __restrict__ Wk,
    const bf16* __restrict__ Wv,
    const float* __restrict__ bq, const float* __restrict__ bk,
    const float* __restrict__ bv,
    bf16* __restrict__ q_ws, bf16* __restrict__ k_ws, bf16* __restrict__ vt_ws)
{
    int m0 = blockIdx.x * 128;
    int n0 = blockIdx.y * 128;
    int sec = n0 >> 10;
    int nw0 = n0 & 1023;
    const bf16* W     = (sec == 0) ? Wq : (sec == 1) ? Wk : Wv;
    const float* bias = (sec == 0) ? bq : (sec == 1) ? bk : bv;

    __shared__ bf16 As[3][128][32];
    __shared__ bf16 Bs[3][128][32];

    int tid = threadIdx.x;
    int lane = tid & 63, w = tid >> 6;
    int l15 = lane & 15, quad = lane >> 4;
    int wm = (w >> 1) * 64, wn = (w & 1) * 64;

    floatx4 acc[4][4];
    #pragma unroll
    for (int i = 0; i < 4; i++)
        #pragma unroll
        for (int j = 0; j < 4; j++) acc[i][j] = (floatx4){0.f, 0.f, 0.f, 0.f};

    GEMM_CORE(xb, W, m0, nw0)

    if (sec < 2) {
        bf16* outp = (sec == 0) ? q_ws : k_ws;
        float inv[2];
        inv[0] = __expf(-(float)l15 * (9.210340371976184f / 32.0f));
        inv[1] = __expf(-(float)(16 + l15) * (9.210340371976184f / 32.0f));
        #pragma unroll
        for (int mt = 0; mt < 4; mt++) {
            #pragma unroll
            for (int r = 0; r < 4; r++) {
                int m = m0 + wm + mt * 16 + quad * 4 + r;
                int bb = m >> 11, s = m & 2047;
                #pragma unroll
                for (int nt = 0; nt < 2; nt++) {
                    int nl1 = nw0 + wn + nt * 16 + l15;
                    int nl2 = nl1 + 32;
                    float x1 = acc[mt][nt][r] + bias[nl1];
                    float x2 = acc[mt][nt + 2][r] + bias[nl2];
                    float ang = (float)s * inv[nt];
                    float sn, cs;
                    __sincosf(ang, &sn, &cs);
                    int hh = nl1 >> 6, d = nl1 & 63;
                    size_t base = ((size_t)(bb * 16 + hh) * 2048 + s) * 64;
                    outp[base + d]      = (bf16)(x1 * cs - x2 * sn);
                    outp[base + d + 32] = (bf16)(x2 * cs + x1 * sn);
                }
            }
        }
    } else {
        #pragma unroll
        for (int mt = 0; mt < 4; mt++) {
            int mbase = m0 + wm + mt * 16 + quad * 4;
            int bb = mbase >> 11, s0 = mbase & 2047;
            #pragma unroll
            for (int nt = 0; nt < 4; nt++) {
                int nl = nw0 + wn + nt * 16 + l15;
                int hh = nl >> 6, d = nl & 63;
                bf16x4 pk;
                #pragma unroll
                for (int r = 0; r < 4; r++) pk[r] = (bf16)(acc[mt][nt][r] + bias[nl]);
                *(bf16x4*)&vt_ws[((size_t)(bb * 16 + hh) * 64 + d) * 2048 + s0] = pk;
            }
        }
    }
}

// ---------------------------------------------------------------------------
// Output projection (fast): out[m][n] = sum_k O[m][k]*Wo[n][k] + bo[n]
// ---------------------------------------------------------------------------
__global__ __launch_bounds__(256) void gemm_out_fast(
    const bf16* __restrict__ A, const bf16* __restrict__ W,
    const float* __restrict__ bias, float* __restrict__ out)
{
    int m0 = blockIdx.x * 128;
    int n0 = blockIdx.y * 128;

    __shared__ bf16 As[3][128][32];
    __shared__ bf16 Bs[3][128][32];

    int tid = threadIdx.x;
    int lane = tid & 63, w = tid >> 6;
    int l15 = lane & 15, quad = lane >> 4;
    int wm = (w >> 1) * 64, wn = (w & 1) * 64;

    floatx4 acc[4][4];
    #pragma unroll
    for (int i = 0; i < 4; i++)
        #pragma unroll
        for (int j = 0; j < 4; j++) acc[i][j] = (floatx4){0.f, 0.f, 0.f, 0.f};

    GEMM_CORE(A, W, m0, n0)

    #pragma unroll
    for (int mt = 0; mt < 4; mt++) {
        #pragma unroll
        for (int r = 0; r < 4; r++) {
            int m = m0 + wm + mt * 16 + quad * 4 + r;
            #pragma unroll
            for (int nt = 0; nt < 4; nt++) {
                int nl = n0 + wn + nt * 16 + l15;
                out[(size_t)m * 1024 + nl] = acc[mt][nt][r] + bias[nl];
            }
        }
    }
}

// ===========================================================================
// FALLBACK GEMMs (f32 W staged with in-flight cvt) — used if ws too small
// ===========================================================================
__global__ __launch_bounds__(256) void gemm_qkv_f32w(
    const bf16* __restrict__ xb,
    const float* __restrict__ Wq, const float* __restrict__ Wk,
    const float* __restrict__ Wv,
    const float* __restrict__ bq, const float* __restrict__ bk,
    const float* __restrict__ bv,
    bf16* __restrict__ q_ws, bf16* __restrict__ k_ws, bf16* __restrict__ vt_ws)
{
    int m0 = blockIdx.x * 128;
    int n0 = blockIdx.y * 128;
    int sec = n0 >> 10;
    int nw0 = n0 & 1023;
    const float* W    = (sec == 0) ? Wq : (sec == 1) ? Wk : Wv;
    const float* bias = (sec == 0) ? bq : (sec == 1) ? bk : bv;

    __shared__ bf16 As[128][72];
    __shared__ bf16 Bs[128][72];

    int tid = threadIdx.x;
    int lane = tid & 63, w = tid >> 6;
    int l15 = lane & 15, quad = lane >> 4;
    int wm = (w >> 1) * 64, wn = (w & 1) * 64;
    int sr = tid >> 1;
    int sk = (tid & 1) * 32;

    floatx4 acc[4][4];
    #pragma unroll
    for (int i = 0; i < 4; i++)
        #pragma unroll
        for (int j = 0; j < 4; j++) acc[i][j] = (floatx4){0.f, 0.f, 0.f, 0.f};

    for (int k0 = 0; k0 < 1024; k0 += 64) {
        __syncthreads();
        const bf16* ap = &xb[(size_t)(m0 + sr) * 1024 + k0 + sk];
        bf16x8 a0 = *(const bf16x8*)(ap);
        bf16x8 a1 = *(const bf16x8*)(ap + 8);
        bf16x8 a2 = *(const bf16x8*)(ap + 16);
        bf16x8 a3 = *(const bf16x8*)(ap + 24);
        const float* wp = &W[(size_t)(nw0 + sr) * 1024 + k0 + sk];
        bf16x8 bv_[4];
        #pragma unroll
        for (int c = 0; c < 4; c++) {
            float4 f0 = *(const float4*)(wp + c * 8);
            float4 f1 = *(const float4*)(wp + c * 8 + 4);
            bf16x8 t;
            t[0] = (bf16)f0.x; t[1] = (bf16)f0.y; t[2] = (bf16)f0.z; t[3] = (bf16)f0.w;
            t[4] = (bf16)f1.x; t[5] = (bf16)f1.y; t[6] = (bf16)f1.z; t[7] = (bf16)f1.w;
            bv_[c] = t;
        }
        *(bf16x8*)&As[sr][sk + 0]  = a0;
        *(bf16x8*)&As[sr][sk + 8]  = a1;
        *(bf16x8*)&As[sr][sk + 16] = a2;
        *(bf16x8*)&As[sr][sk + 24] = a3;
        #pragma unroll
        for (int c = 0; c < 4; c++) *(bf16x8*)&Bs[sr][sk + c * 8] = bv_[c];
        __syncthreads();
        #pragma unroll
        for (int kk = 0; kk < 64; kk += 32) {
            bf16x8 af[4], bfr[4];
            #pragma unroll
            for (int mt = 0; mt < 4; mt++)
                af[mt] = *(const bf16x8*)&As[wm + mt * 16 + l15][kk + quad * 8];
            #pragma unroll
            for (int nt = 0; nt < 4; nt++)
                bfr[nt] = *(const bf16x8*)&Bs[wn + nt * 16 + l15][kk + quad * 8];
            #pragma unroll
            for (int mt = 0; mt < 4; mt++)
                #pragma unroll
                for (int nt = 0; nt < 4; nt++)
                    acc[mt][nt] = MFMA16(af[mt], bfr[nt], acc[mt][nt]);
        }
    }

    if (sec < 2) {
        bf16* outp = (sec == 0) ? q_ws : k_ws;
        float inv[2];
        inv[0] = __expf(-(float)l15 * (9.210340371976184f / 32.0f));
        inv[1] = __expf(-(float)(16 + l15) * (9.210340371976184f / 32.0f));
        #pragma unroll
        for (int mt = 0; mt < 4; mt++) {
            #pragma unroll
            for (int r = 0; r < 4; r++) {
                int m = m0 + wm + mt * 16 + quad * 4 + r;
                int bb = m >> 11, s = m & 2047;
                #pragma unroll
                for (int nt = 0; nt < 2; nt++) {
                    int nl1 = nw0 + wn + nt * 16 + l15;
                    int nl2 = nl1 + 32;
                    float x1 = acc[mt][nt][r] + bias[nl1];
                    float x2 = acc[mt][nt + 2][r] + bias[nl2];
                    float ang = (float)s * inv[nt];
                    float sn, cs;
                    __sincosf(ang, &sn, &cs);
                    int hh = nl1 >> 6, d = nl1 & 63;
                    size_t base = ((size_t)(bb * 16 + hh) * 2048 + s) * 64;
                    outp[base + d]      = (bf16)(x1 * cs - x2 * sn);
                    outp[base + d + 32] = (bf16)(x2 * cs + x1 * sn);
                }
            }
        }
    } else {
        #pragma unroll
        for (int mt = 0; mt < 4; mt++) {
            int mbase = m0 + wm + mt * 16 + quad * 4;
            int bb = mbase >> 11, s0 = mbase & 2047;
            #pragma unroll
            for (int nt = 0; nt < 4; nt++) {
                int nl = nw0 + wn + nt * 16 + l15;
                int hh = nl >> 6, d = nl & 63;
                bf16x4 pk;
                #pragma unroll
                for (int r = 0; r < 4; r++) pk[r] = (bf16)(acc[mt][nt][r] + bias[nl]);
                *(bf16x4*)&vt_ws[((size_t)(bb * 16 + hh) * 64 + d) * 2048 + s0] = pk;
            }
        }
    }
}

__global__ __launch_bounds__(256) void gemm_out_f32w(
    const bf16* __restrict__ A, const float* __restrict__ W,
    const float* __restrict__ bias, float* __restrict__ out)
{
    int m0 = blockIdx.x * 128;
    int n0 = blockIdx.y * 128;

    __shared__ bf16 As[128][72];
    __shared__ bf16 Bs[128][72];

    int tid = threadIdx.x;
    int lane = tid & 63, w = tid >> 6;
    int l15 = lane & 15, quad = lane >> 4;
    int wm = (w >> 1) * 64, wn = (w & 1) * 64;
    int sr = tid >> 1;
    int sk = (tid & 1) * 32;

    floatx4 acc[4][4];
    #pragma unroll
    for (int i = 0; i < 4; i++)
        #pragma unroll
        for (int j = 0; j < 4; j++) acc[i][j] = (floatx4){0.f, 0.f, 0.f, 0.f};

    for (int k0 = 0; k0 < 1024; k0 += 64) {
        __syncthreads();
        const bf16* ap = &A[(size_t)(m0 + sr) * 1024 + k0 + sk];
        bf16x8 a0 = *(const bf16x8*)(ap);
        bf16x8 a1 = *(const bf16x8*)(ap + 8);
        bf16x8 a2 = *(const bf16x8*)(ap + 16);
        bf16x8 a3 = *(const bf16x8*)(ap + 24);
        const float* wp = &W[(size_t)(n0 + sr) * 1024 + k0 + sk];
        bf16x8 bv_[4];
        #pragma unroll
        for (int c = 0; c < 4; c++) {
            float4 f0 = *(const float4*)(wp + c * 8);
            float4 f1 = *(const float4*)(wp + c * 8 + 4);
            bf16x8 t;
            t[0] = (bf16)f0.x; t[1] = (bf16)f0.y; t[2] = (bf16)f0.z; t[3] = (bf16)f0.w;
            t[4] = (bf16)f1.x; t[5] = (bf16)f1.y; t[6] = (bf16)f1.z; t[7] = (bf16)f1.w;
            bv_[c] = t;
        }
        *(bf16x8*)&As[sr][sk + 0]  = a0;
        *(bf16x8*)&As[sr][sk + 8]  = a1;
        *(bf16x8*)&As[sr][sk + 16] = a2;
        *(bf16x8*)&As[sr][sk + 24] = a3;
        #pragma unroll
        for (int c = 0; c < 4; c++) *(bf16x8*)&Bs[sr][sk + c * 8] = bv_[c];
        __syncthreads();
        #pragma unroll
        for (int kk = 0; kk < 64; kk += 32) {
            bf16x8 af[4], bfr[4];
            #pragma unroll
            for (int mt = 0; mt < 4; mt++)
                af[mt] = *(const bf16x8*)&As[wm + mt * 16 + l15][kk + quad * 8];
            #pragma unroll
            for (int nt = 0; nt < 4; nt++)
                bfr[nt] = *(const bf16x8*)&Bs[wn + nt * 16 + l15][kk + quad * 8];
            #pragma unroll
            for (int mt = 0; mt < 4; mt++)
                #pragma unroll
                for (int nt = 0; nt < 4; nt++)
                    acc[mt][nt] = MFMA16(af[mt], bfr[nt], acc[mt][nt]);
        }
    }

    #pragma unroll
    for (int mt = 0; mt < 4; mt++) {
        #pragma unroll
        for (int r = 0; r < 4; r++) {
            int m = m0 + wm + mt * 16 + quad * 4 + r;
            #pragma unroll
            for (int nt = 0; nt < 4; nt++) {
                int nl = n0 + wn + nt * 16 + l15;
                out[(size_t)m * 1024 + nl] = acc[mt][nt][r] + bias[nl];
            }
        }
    }
}

// ---------------------------------------------------------------------------
// MFMA flash attention V13 (verified best, round 13): KVBLK=128, qt-pairing,
// counted-vmcnt ping-pong, fixed-max softmax + ones-MFMA l, chunk-XOR
// swizzles (K 3-bit, V/Ps 4-bit), XCD pinning, unroll-2 static buffers.
// LDS: Ks[2][128][64] 32KB + Vt[2][64][128] 32KB + Ps[4][16][128] 16KB
// = 81920 B -> 2 blocks/CU.  (Unchanged this round.)
// ---------------------------------------------------------------------------
__global__ __launch_bounds__(256, 2) void attn_kernel(
    const bf16* __restrict__ q_ws, const bf16* __restrict__ k_ws,
    const bf16* __restrict__ vt_ws, bf16* __restrict__ o_ws)
{
    __shared__ bf16 Ks[2][128][64];   // [buf][key][d], chunk-swizzled (3-bit)
    __shared__ bf16 Vt[2][64][128];   // [buf][d][key], chunk-swizzled (4-bit)
    __shared__ bf16 Ps[4][16][128];   // per-wave P [q][key], 4-bit XOR swizzle

    int tid = threadIdx.x;
    int w = tid >> 6, lane = tid & 63;
    int l15 = lane & 15, quad = lane >> 4;

    int bid = blockIdx.x;            // 0..511
    int g = bid & 31;                // bh; bid%8==g%8 -> same XCD per bh
    int x = bid >> 5;                // 0..15
    int bb = g >> 4, h = g & 15;
    const bf16* qp = q_ws + (size_t)g * 2048 * 64;
    const bf16* kp = k_ws + (size_t)g * 2048 * 64;
    const bf16* vp = vt_ws + (size_t)g * 64 * 2048;

    // staging maps: wave w stages 4 segments (of 16) for K and for V.
    // One segment = 64 lanes x 16B = 512 bf16. Segment s of wave w covers
    // 16B-units u = (w*4+s)*64 + lane.
    int kr[4], kc[4], vr[4], vc[4];
    #pragma unroll
    for (int s = 0; s < 4; s++) {
        int u = (w * 4 + s) * 64 + lane;
        kr[s] = u >> 3; kc[s] = (u & 7) ^ (kr[s] & 7);
        vr[s] = u >> 4; vc[s] = (u & 15) ^ (vr[s] & 15);
    }
    int od0 = (w * 4) * 512;         // bf16 offset of wave's first segment

    const float SCL = 0.125f * 1.4426950408889634f;   // (1/sqrt(HD))*log2(e)
    const float MFIX = 20.0f;        // fixed exp2-domain shift (folded in C-init)
    int lx7 = l15 & 7;               // K-read swizzle key (row&7 == l15&7)

    bf16x8 ones8;
    #pragma unroll
    for (int i = 0; i < 8; i++) ones8[i] = (bf16)1.0f;

    #pragma unroll 1
    for (int pass = 0; pass < 2; ++pass) {
        int qt = pass ? (31 - x) : x;
        int qrow = qt * 64 + w * 16;
        int nkt = (qt + 2) >> 1;     // 128-key tiles covering keys 0..qt*64+63

        // Q B-frags resident, pre-scaled
        bf16x8 qf0 = scale8(*(const bf16x8*)&qp[(size_t)(qrow + l15) * 64 + quad * 8], SCL);
        bf16x8 qf1 = scale8(*(const bf16x8*)&qp[(size_t)(qrow + l15) * 64 + 32 + quad * 8], SCL);

        floatx4 lacc = (floatx4){0.f, 0.f, 0.f, 0.f};   // ones-MFMA l accum
        floatx4 acc[4];
        #pragma unroll
        for (int nt = 0; nt < 4; nt++) acc[nt] = (floatx4){0.f, 0.f, 0.f, 0.f};

        // running stage-source pointers (advance per 128-key tile:
        // K +8192 elems; V +128 key-cols)
        const bf16* kst[4];
        const bf16* vst[4];
        #pragma unroll
        for (int s = 0; s < 4; s++) {
            kst[s] = kp + (size_t)kr[s] * 64 + kc[s] * 8;
            vst[s] = vp + (size_t)vr[s] * 2048 + vc[s] * 8;
        }

        // prologue: stage kt=0 into buf 0.
        #pragma unroll
        for (int s = 0; s < 4; s++) {
            load_lds16(kst[s], &Ks[0][0][0] + od0 + s * 512);
            load_lds16(vst[s], &Vt[0][0][0] + od0 + s * 512);
            kst[s] += 8192; vst[s] += 128;
        }

        #pragma unroll 2
        for (int kt = 0; kt < nkt; kt++) {
            int buf = kt & 1;        // compile-time per unrolled copy
            if (kt + 1 < nkt) {
                #pragma unroll
                for (int s = 0; s < 4; s++) {
                    load_lds16(kst[s], &Ks[buf ^ 1][0][0] + od0 + s * 512);
                    load_lds16(vst[s], &Vt[buf ^ 1][0][0] + od0 + s * 512);
                    kst[s] += 8192; vst[s] += 128;
                }
                WAITV8_BAR();
            } else {
                WAITV0_BAR();
            }

            int kt0 = kt * 128;

            // S^T = K * Q^T : 8 key-blocks of 16, per lane 4 keys x 1 query.
            floatx4 st[8];
            __builtin_amdgcn_s_setprio(1);
            #pragma unroll
            for (int kb = 0; kb < 8; kb++) {
                int row = kb * 16 + l15;
                bf16x8 a0 = *(const bf16x8*)&Ks[buf][row][(quad ^ lx7) * 8];
                bf16x8 a1 = *(const bf16x8*)&Ks[buf][row][((quad + 4) ^ lx7) * 8];
                floatx4 z = {-MFIX, -MFIX, -MFIX, -MFIX};
                z = MFMA16(a0, qf0, z);
                z = MFMA16(a1, qf1, z);
                st[kb] = z;
            }
            __builtin_amdgcn_s_setprio(0);
            if (kt0 + 127 > qrow) {  // tile reaches past the diagonal: mask
                int q = qrow + l15;
                #pragma unroll
                for (int kb = 0; kb < 8; kb++)
                    #pragma unroll
                    for (int rr = 0; rr < 4; rr++) {
                        int key = kt0 + kb * 16 + quad * 4 + rr;
                        if (key > q) st[kb][rr] = -1e30f;
                    }
            }

            // fixed-max softmax; Ps write at 4-bit chunk-XOR swizzled column
            #pragma unroll
            for (int kb = 0; kb < 8; kb++) {
                bf16x4 pk;
                #pragma unroll
                for (int rr = 0; rr < 4; rr++)
                    pk[rr] = (bf16)exp2f(st[kb][rr]);
                int ch = kb * 2 + (quad >> 1);
                *(bf16x4*)&Ps[w][l15][((ch ^ l15) << 3) + ((quad & 1) << 2)] = pk;
            }

            // O^T += V^T * P^T over 4 key-slices of 32; l via ones-MFMA.
            bf16x8 pb[4];
            #pragma unroll
            for (int ks = 0; ks < 4; ks++)
                pb[ks] = *(const bf16x8*)&Ps[w][l15][((ks * 4 + quad) ^ l15) << 3];
            __builtin_amdgcn_s_setprio(1);
            #pragma unroll
            for (int nt = 0; nt < 4; nt++) {
                int row = nt * 16 + l15;
                #pragma unroll
                for (int ks = 0; ks < 4; ks++) {
                    bf16x8 v = *(const bf16x8*)&Vt[buf][row][((ks * 4 + quad) ^ l15) * 8];
                    acc[nt] = MFMA16(v, pb[ks], acc[nt]);
                }
            }
            #pragma unroll
            for (int ks = 0; ks < 4; ks++)
                lacc = MFMA16(ones8, pb[ks], lacc);
            __builtin_amdgcn_s_setprio(0);

            TRAIL_BAR();
        }

        // lacc rows are all the per-query (l15) sum: no cross-lane reduce.
        float inv = 1.f / lacc[0];
        int s = qrow + l15;
        #pragma unroll
        for (int nt = 0; nt < 4; nt++) {
            bf16x4 pk;
            #pragma unroll
            for (int rr = 0; rr < 4; rr++) pk[rr] = (bf16)(acc[nt][rr] * inv);
            *(bf16x4*)&o_ws[((size_t)(bb * 2048 + s)) * 1024 + h * 64 + nt * 16 + quad * 4] = pk;
        }
    }
}

// ---------------------------------------------------------------------------
extern "C" void kernel_launch(void* const* d_in, const int* in_sizes, int n_in,
                              void* d_out, int out_size, void* d_ws, size_t ws_size,
                              hipStream_t stream) {
    const float* x  = (const float*)d_in[0];
    const float* Wq = (const float*)d_in[1];
    const float* bq = (const float*)d_in[2];
    const float* Wk = (const float*)d_in[3];
    const float* bk = (const float*)d_in[4];
    const float* Wv = (const float*)d_in[5];
    const float* bv = (const float*)d_in[6];
    const float* Wo = (const float*)d_in[7];
    const float* bo = (const float*)d_in[8];
    float* out = (float*)d_out;

    const size_t NELEM = (size_t)2 * 2048 * 1024;   // 4,194,304
    const size_t WELEM = (size_t)1024 * 1024;
    bf16* xb    = (bf16*)d_ws;          // 8MB; reused as o_ws after qkv
    bf16* q_ws  = xb + NELEM;
    bf16* k_ws  = q_ws + NELEM;
    bf16* vt_ws = k_ws + NELEM;         // (B,NH,HD,S)
    bf16* o_ws  = xb;
    bf16* wqb   = vt_ws + NELEM;        // +2MB each
    bf16* wkb   = wqb + WELEM;
    bf16* wvb   = wkb + WELEM;
    bf16* wob   = wvb + WELEM;          // ends at 40MB

    bool fast = ws_size >= (size_t)40 * 1024 * 1024;   // constant across calls

    if (fast) {
        cvt_all_kernel<<<8192, 256, 0, stream>>>(x, Wq, Wk, Wv, Wo,
                                                 xb, wqb, wkb, wvb, wob);
        gemm_qkv_fast<<<dim3(32, 24), 256, 0, stream>>>(
            xb, wqb, wkb, wvb, bq, bk, bv, q_ws, k_ws, vt_ws);
        attn_kernel<<<512, 256, 0, stream>>>(q_ws, k_ws, vt_ws, o_ws);
        gemm_out_fast<<<dim3(32, 8), 256, 0, stream>>>(o_ws, wob, bo, out);
    } else {
        cvt_kernel<<<4096, 256, 0, stream>>>(x, xb);
        gemm_qkv_f32w<<<dim3(32, 24), 256, 0, stream>>>(
            xb, Wq, Wk, Wv, bq, bk, bv, q_ws, k_ws, vt_ws);
        attn_kernel<<<512, 256, 0, stream>>>(q_ws, k_ws, vt_ws, o_ws);
        gemm_out_f32w<<<dim3(32, 8), 256, 0, stream>>>(o_ws, Wo, bo, out);
    }
}

// Round 17
// 188.751 us; speedup vs baseline: 1.0472x; 1.0262x over previous
//
#include <hip/hip_runtime.h>

// B=2, S=2048, H=1024, NH=16, HD=64. f32 in/out; bf16 intermediates + MFMA.
// MFMA 16x16x32 bf16 layouts (m89/m91):
//   A: lane holds A[m=lane&15][k=quad*8+j]   B: B[k=quad*8+j][n=lane&15]
//   C/D: lane reg r -> row=quad*4+r, col=lane&15
typedef __bf16 bf16;
typedef __bf16 bf16x4 __attribute__((ext_vector_type(4)));
typedef __bf16 bf16x8 __attribute__((ext_vector_type(8)));
typedef float floatx4 __attribute__((ext_vector_type(4)));

#define MFMA16(a, b, c) __builtin_amdgcn_mfma_f32_16x16x32_bf16(a, b, c, 0, 0, 0)

__device__ __forceinline__ void load_lds16(const void* g, void* l) {
    // async global->LDS DMA, 16B/lane; dest = wave-uniform base + lane*16
    __builtin_amdgcn_global_load_lds(
        (const __attribute__((address_space(1))) unsigned int*)g,
        (__attribute__((address_space(3))) unsigned int*)l, 16, 0, 0);
}

__device__ __forceinline__ bf16x8 scale8(bf16x8 a, float s) {
    bf16x8 o;
    #pragma unroll
    for (int i = 0; i < 8; i++) o[i] = (bf16)((float)a[i] * s);
    return o;
}

// counted-vmcnt barrier pair (T3+T4): loads stay in flight across barriers.
#define WAITV8_BAR()  do { asm volatile("s_waitcnt vmcnt(8)" ::: "memory"); \
                           __builtin_amdgcn_s_barrier();                    \
                           __builtin_amdgcn_sched_barrier(0); } while (0)
#define WAITV4_BAR()  do { asm volatile("s_waitcnt vmcnt(4)" ::: "memory"); \
                           __builtin_amdgcn_s_barrier();                    \
                           __builtin_amdgcn_sched_barrier(0); } while (0)
#define WAITV2_BAR()  do { asm volatile("s_waitcnt vmcnt(2)" ::: "memory"); \
                           __builtin_amdgcn_s_barrier();                    \
                           __builtin_amdgcn_sched_barrier(0); } while (0)
#define WAITV0_BAR()  do { asm volatile("s_waitcnt vmcnt(0)" ::: "memory"); \
                           __builtin_amdgcn_s_barrier();                    \
                           __builtin_amdgcn_sched_barrier(0); } while (0)
#define TRAIL_BAR()   do { __builtin_amdgcn_sched_barrier(0);               \
                           asm volatile("s_waitcnt lgkmcnt(0)" ::: "memory"); \
                           __builtin_amdgcn_s_barrier(); } while (0)

// ---------------------------------------------------------------------------
// cvt: x (4096 blk), Wq/Wk/Wv/Wo (1024 blk each) f32 -> bf16
// ---------------------------------------------------------------------------
__global__ __launch_bounds__(256) void cvt_all_kernel(
    const float* __restrict__ x, const float* __restrict__ wq,
    const float* __restrict__ wk, const float* __restrict__ wv,
    const float* __restrict__ wo,
    bf16* __restrict__ xb, bf16* __restrict__ wqb, bf16* __restrict__ wkb,
    bf16* __restrict__ wvb, bf16* __restrict__ wob)
{
    int bid = blockIdx.x;
    const float* src; bf16* dst; int off;
    if (bid < 4096)      { src = x;  dst = xb;  off = bid; }
    else if (bid < 5120) { src = wq; dst = wqb; off = bid - 4096; }
    else if (bid < 6144) { src = wk; dst = wkb; off = bid - 5120; }
    else if (bid < 7168) { src = wv; dst = wvb; off = bid - 6144; }
    else                 { src = wo; dst = wob; off = bid - 7168; }
    int idx = (off * 256 + threadIdx.x) * 4;
    float4 v = *(const float4*)&src[idx];
    bf16x4 o;
    o[0] = (bf16)v.x; o[1] = (bf16)v.y; o[2] = (bf16)v.z; o[3] = (bf16)v.w;
    *(bf16x4*)&dst[idx] = o;
}

__global__ __launch_bounds__(256) void cvt_kernel(const float* __restrict__ x,
                                                  bf16* __restrict__ xb) {
    int idx = (blockIdx.x * 256 + threadIdx.x) * 4;
    float4 v = *(const float4*)&x[idx];
    bf16x4 o;
    o[0] = (bf16)v.x; o[1] = (bf16)v.y; o[2] = (bf16)v.z; o[3] = (bf16)v.w;
    *(bf16x4*)&xb[idx] = o;
}

// ===========================================================================
// FAST qkv GEMM: 2-phase BK=32 ping-pong with COUNTED vmcnt (T3+T4) + T5.
// (round-13 exact — verified fast)
// ===========================================================================

#define PREP_STAGE()                                                          \
    int u0 = w * 128 + lane;                                                  \
    int u1 = u0 + 64;                                                         \
    int r0_ = u0 >> 2, c0_ = ((u0 & 3) ^ ((r0_ >> 1) & 3)) * 8;               \
    int r1_ = u1 >> 2, c1_ = ((u1 & 3) ^ ((r1_ >> 1) & 3)) * 8;               \
    int du0 = w * 1024;                                                       \
    int du1 = du0 + 512;

#define STAGE_PF(Asrc, Bsrc, arow, brow, sbuf, kk0)                           \
    do {                                                                      \
        load_lds16(&Asrc[(size_t)((arow) + r0_) * 1024 + (kk0) + c0_],        \
                   &As[sbuf][0][0] + du0);                                    \
        load_lds16(&Asrc[(size_t)((arow) + r1_) * 1024 + (kk0) + c1_],        \
                   &As[sbuf][0][0] + du1);                                    \
        load_lds16(&Bsrc[(size_t)((brow) + r0_) * 1024 + (kk0) + c0_],        \
                   &Bs[sbuf][0][0] + du0);                                    \
        load_lds16(&Bsrc[(size_t)((brow) + r1_) * 1024 + (kk0) + c1_],        \
                   &Bs[sbuf][0][0] + du1);                                    \
    } while (0)

#define GEMM_CORE(Asrc, Bsrc, arow, brow)                                     \
    PREP_STAGE()                                                              \
    STAGE_PF(Asrc, Bsrc, arow, brow, 0, 0);                                   \
    _Pragma("unroll 2")                                                       \
    for (int s = 0; s < 32; s++) {                                            \
        int sb = s & 1;                                                       \
        if (s + 1 < 32) {                                                     \
            STAGE_PF(Asrc, Bsrc, arow, brow, sb ^ 1, (s + 1) * 32);           \
            WAITV4_BAR();                                                     \
        } else {                                                              \
            WAITV0_BAR();                                                     \
        }                                                                     \
        bf16x8 af[4], bfr[4];                                                 \
        _Pragma("unroll")                                                     \
        for (int mt = 0; mt < 4; mt++) {                                      \
            int row = wm + mt * 16 + l15;                                     \
            af[mt] = *(const bf16x8*)&As[sb][row][(quad ^ ((row >> 1) & 3)) * 8]; \
        }                                                                     \
        _Pragma("unroll")                                                     \
        for (int nt = 0; nt < 4; nt++) {                                      \
            int row = wn + nt * 16 + l15;                                     \
            bfr[nt] = *(const bf16x8*)&Bs[sb][row][(quad ^ ((row >> 1) & 3)) * 8]; \
        }                                                                     \
        __builtin_amdgcn_s_setprio(1);                                        \
        _Pragma("unroll")                                                     \
        for (int mt = 0; mt < 4; mt++)                                        \
            _Pragma("unroll")                                                 \
            for (int nt = 0; nt < 4; nt++)                                    \
                acc[mt][nt] = MFMA16(af[mt], bfr[nt], acc[mt][nt]);           \
        __builtin_amdgcn_s_setprio(0);                                        \
        TRAIL_BAR();                                                          \
    }

// ---------------------------------------------------------------------------
// QKV projection + bias + fused RoPE (q,k) + transposed V store.
// q_ws,k_ws: (B,NH,S,HD); vt_ws: (B,NH,HD,S). All-bf16 inputs.
// ---------------------------------------------------------------------------
__global__ __launch_bounds__(256) void gemm_qkv_fast(
    const bf16* __restrict__ xb,
    const bf16* __restrict__ Wq, const bf16* __restrict__ Wk,
    const bf16* __restrict__ Wv,
    const float* __restrict__ bq, const float* __restrict__ bk,
    const float* __restrict__ bv,
    bf16* __restrict__ q_ws, bf16* __restrict__ k_ws, bf16* __restrict__ vt_ws)
{
    int m0 = blockIdx.x * 128;
    int n0 = blockIdx.y * 128;
    int sec = n0 >> 10;
    int nw0 = n0 & 1023;
    const bf16* W     = (sec == 0) ? Wq : (sec == 1) ? Wk : Wv;
    const float* bias = (sec == 0) ? bq : (sec == 1) ? bk : bv;

    __shared__ bf16 As[2][128][32];
    __shared__ bf16 Bs[2][128][32];

    int tid = threadIdx.x;
    int lane = tid & 63, w = tid >> 6;
    int l15 = lane & 15, quad = lane >> 4;
    int wm = (w >> 1) * 64, wn = (w & 1) * 64;

    floatx4 acc[4][4];
    #pragma unroll
    for (int i = 0; i < 4; i++)
        #pragma unroll
        for (int j = 0; j < 4; j++) acc[i][j] = (floatx4){0.f, 0.f, 0.f, 0.f};

    GEMM_CORE(xb, W, m0, nw0)

    if (sec < 2) {
        bf16* outp = (sec == 0) ? q_ws : k_ws;
        float inv[2];
        inv[0] = __expf(-(float)l15 * (9.210340371976184f / 32.0f));
        inv[1] = __expf(-(float)(16 + l15) * (9.210340371976184f / 32.0f));
        #pragma unroll
        for (int mt = 0; mt < 4; mt++) {
            #pragma unroll
            for (int r = 0; r < 4; r++) {
                int m = m0 + wm + mt * 16 + quad * 4 + r;
                int bb = m >> 11, s = m & 2047;
                #pragma unroll
                for (int nt = 0; nt < 2; nt++) {
                    int nl1 = nw0 + wn + nt * 16 + l15;
                    int nl2 = nl1 + 32;
                    float x1 = acc[mt][nt][r] + bias[nl1];
                    float x2 = acc[mt][nt + 2][r] + bias[nl2];
                    float ang = (float)s * inv[nt];
                    float sn, cs;
                    __sincosf(ang, &sn, &cs);
                    int hh = nl1 >> 6, d = nl1 & 63;
                    size_t base = ((size_t)(bb * 16 + hh) * 2048 + s) * 64;
                    outp[base + d]      = (bf16)(x1 * cs - x2 * sn);
                    outp[base + d + 32] = (bf16)(x2 * cs + x1 * sn);
                }
            }
        }
    } else {
        #pragma unroll
        for (int mt = 0; mt < 4; mt++) {
            int mbase = m0 + wm + mt * 16 + quad * 4;
            int bb = mbase >> 11, s0 = mbase & 2047;
            #pragma unroll
            for (int nt = 0; nt < 4; nt++) {
                int nl = nw0 + wn + nt * 16 + l15;
                int hh = nl >> 6, d = nl & 63;
                bf16x4 pk;
                #pragma unroll
                for (int r = 0; r < 4; r++) pk[r] = (bf16)(acc[mt][nt][r] + bias[nl]);
                *(bf16x4*)&vt_ws[((size_t)(bb * 16 + hh) * 64 + d) * 2048 + s0] = pk;
            }
        }
    }
}

// ---------------------------------------------------------------------------
// Output projection V3: 512 threads / 8 waves on the 128x128 tile.
// V16 bug fixed: one BK=32 half-tile = 128 rows x 32 cols = 512 16B-units,
// so each wave must stage TWO segments (8 segs/half total), not one.
// Waves 0-3 stage A segs {2(w&3), 2(w&3)+1}; waves 4-7 stage B same.
// Same verified swizzle math as PREP_STAGE. vmcnt: 2 loads/wave/tile ->
// counted WAITV2_BAR ping-pong (2 prefetch loads stay in flight).
// Each wave computes 32x64 (acc 2x4). 8 waves/CU = 2/SIMD (was 1/SIMD).
// LDS 32KB.
// ---------------------------------------------------------------------------
__global__ __launch_bounds__(512) void gemm_out_fast(
    const bf16* __restrict__ A, const bf16* __restrict__ W,
    const float* __restrict__ bias, float* __restrict__ out)
{
    int m0 = blockIdx.x * 128;
    int n0 = blockIdx.y * 128;

    __shared__ bf16 As[2][128][32];
    __shared__ bf16 Bs[2][128][32];

    int tid = threadIdx.x;
    int lane = tid & 63, w = tid >> 6;      // w in 0..7
    int l15 = lane & 15, quad = lane >> 4;
    int wm = (w >> 1) * 32, wn = (w & 1) * 64;

    // staging: wave w stages segments {2(w&3), 2(w&3)+1} of (w<4 ? A : B).
    int u0 = (w & 3) * 128 + lane;          // 16B-unit 0..511 within half
    int u1 = u0 + 64;
    int sr0 = u0 >> 2, sc0 = ((u0 & 3) ^ ((sr0 >> 1) & 3)) * 8;
    int sr1 = u1 >> 2, sc1 = ((u1 & 3) ^ ((sr1 >> 1) & 3)) * 8;
    int du0 = (w & 3) * 1024;               // bf16 dest offsets
    int du1 = du0 + 512;
    const bf16* base = (w < 4) ? &A[(size_t)m0 * 1024] : &W[(size_t)n0 * 1024];
    const bf16* src0 = base + (size_t)sr0 * 1024 + sc0;
    const bf16* src1 = base + (size_t)sr1 * 1024 + sc1;

    floatx4 acc[2][4];
    #pragma unroll
    for (int i = 0; i < 2; i++)
        #pragma unroll
        for (int j = 0; j < 4; j++) acc[i][j] = (floatx4){0.f, 0.f, 0.f, 0.f};

    // prologue: stage tile 0 into buf 0
    {
        bf16* d0 = ((w < 4) ? &As[0][0][0] : &Bs[0][0][0]) + du0;
        bf16* d1 = ((w < 4) ? &As[0][0][0] : &Bs[0][0][0]) + du1;
        load_lds16(src0, d0);
        load_lds16(src1, d1);
    }

    #pragma unroll 2
    for (int s = 0; s < 32; s++) {
        int sb = s & 1;
        if (s + 1 < 32) {
            bf16* d0 = ((w < 4) ? &As[sb ^ 1][0][0] : &Bs[sb ^ 1][0][0]) + du0;
            bf16* d1 = ((w < 4) ? &As[sb ^ 1][0][0] : &Bs[sb ^ 1][0][0]) + du1;
            load_lds16(src0 + (s + 1) * 32, d0);
            load_lds16(src1 + (s + 1) * 32, d1);
            WAITV2_BAR();
        } else {
            WAITV0_BAR();
        }

        bf16x8 af[2], bfr[4];
        #pragma unroll
        for (int mt = 0; mt < 2; mt++) {
            int row = wm + mt * 16 + l15;
            af[mt] = *(const bf16x8*)&As[sb][row][(quad ^ ((row >> 1) & 3)) * 8];
        }
        #pragma unroll
        for (int nt = 0; nt < 4; nt++) {
            int row = wn + nt * 16 + l15;
            bfr[nt] = *(const bf16x8*)&Bs[sb][row][(quad ^ ((row >> 1) & 3)) * 8];
        }
        __builtin_amdgcn_s_setprio(1);
        #pragma unroll
        for (int mt = 0; mt < 2; mt++)
            #pragma unroll
            for (int nt = 0; nt < 4; nt++)
                acc[mt][nt] = MFMA16(af[mt], bfr[nt], acc[mt][nt]);
        __builtin_amdgcn_s_setprio(0);
        TRAIL_BAR();
    }

    #pragma unroll
    for (int mt = 0; mt < 2; mt++) {
        #pragma unroll
        for (int r = 0; r < 4; r++) {
            int m = m0 + wm + mt * 16 + quad * 4 + r;
            #pragma unroll
            for (int nt = 0; nt < 4; nt++) {
                int nl = n0 + wn + nt * 16 + l15;
                out[(size_t)m * 1024 + nl] = acc[mt][nt][r] + bias[nl];
            }
        }
    }
}

// ===========================================================================
// FALLBACK GEMMs (f32 W staged with in-flight cvt) — used if ws too small
// ===========================================================================
__global__ __launch_bounds__(256) void gemm_qkv_f32w(
    const bf16* __restrict__ xb,
    const float* __restrict__ Wq, const float* __restrict__ Wk,
    const float* __restrict__ Wv,
    const float* __restrict__ bq, const float* __restrict__ bk,
    const float* __restrict__ bv,
    bf16* __restrict__ q_ws, bf16* __restrict__ k_ws, bf16* __restrict__ vt_ws)
{
    int m0 = blockIdx.x * 128;
    int n0 = blockIdx.y * 128;
    int sec = n0 >> 10;
    int nw0 = n0 & 1023;
    const float* W    = (sec == 0) ? Wq : (sec == 1) ? Wk : Wv;
    const float* bias = (sec == 0) ? bq : (sec == 1) ? bk : bv;

    __shared__ bf16 As[128][72];
    __shared__ bf16 Bs[128][72];

    int tid = threadIdx.x;
    int lane = tid & 63, w = tid >> 6;
    int l15 = lane & 15, quad = lane >> 4;
    int wm = (w >> 1) * 64, wn = (w & 1) * 64;
    int sr = tid >> 1;
    int sk = (tid & 1) * 32;

    floatx4 acc[4][4];
    #pragma unroll
    for (int i = 0; i < 4; i++)
        #pragma unroll
        for (int j = 0; j < 4; j++) acc[i][j] = (floatx4){0.f, 0.f, 0.f, 0.f};

    for (int k0 = 0; k0 < 1024; k0 += 64) {
        __syncthreads();
        const bf16* ap = &xb[(size_t)(m0 + sr) * 1024 + k0 + sk];
        bf16x8 a0 = *(const bf16x8*)(ap);
        bf16x8 a1 = *(const bf16x8*)(ap + 8);
        bf16x8 a2 = *(const bf16x8*)(ap + 16);
        bf16x8 a3 = *(const bf16x8*)(ap + 24);
        const float* wp = &W[(size_t)(nw0 + sr) * 1024 + k0 + sk];
        bf16x8 bv_[4];
        #pragma unroll
        for (int c = 0; c < 4; c++) {
            float4 f0 = *(const float4*)(wp + c * 8);
            float4 f1 = *(const float4*)(wp + c * 8 + 4);
            bf16x8 t;
            t[0] = (bf16)f0.x; t[1] = (bf16)f0.y; t[2] = (bf16)f0.z; t[3] = (bf16)f0.w;
            t[4] = (bf16)f1.x; t[5] = (bf16)f1.y; t[6] = (bf16)f1.z; t[7] = (bf16)f1.w;
            bv_[c] = t;
        }
        *(bf16x8*)&As[sr][sk + 0]  = a0;
        *(bf16x8*)&As[sr][sk + 8]  = a1;
        *(bf16x8*)&As[sr][sk + 16] = a2;
        *(bf16x8*)&As[sr][sk + 24] = a3;
        #pragma unroll
        for (int c = 0; c < 4; c++) *(bf16x8*)&Bs[sr][sk + c * 8] = bv_[c];
        __syncthreads();
        #pragma unroll
        for (int kk = 0; kk < 64; kk += 32) {
            bf16x8 af[4], bfr[4];
            #pragma unroll
            for (int mt = 0; mt < 4; mt++)
                af[mt] = *(const bf16x8*)&As[wm + mt * 16 + l15][kk + quad * 8];
            #pragma unroll
            for (int nt = 0; nt < 4; nt++)
                bfr[nt] = *(const bf16x8*)&Bs[wn + nt * 16 + l15][kk + quad * 8];
            #pragma unroll
            for (int mt = 0; mt < 4; mt++)
                #pragma unroll
                for (int nt = 0; nt < 4; nt++)
                    acc[mt][nt] = MFMA16(af[mt], bfr[nt], acc[mt][nt]);
        }
    }

    if (sec < 2) {
        bf16* outp = (sec == 0) ? q_ws : k_ws;
        float inv[2];
        inv[0] = __expf(-(float)l15 * (9.210340371976184f / 32.0f));
        inv[1] = __expf(-(float)(16 + l15) * (9.210340371976184f / 32.0f));
        #pragma unroll
        for (int mt = 0; mt < 4; mt++) {
            #pragma unroll
            for (int r = 0; r < 4; r++) {
                int m = m0 + wm + mt * 16 + quad * 4 + r;
                int bb = m >> 11, s = m & 2047;
                #pragma unroll
                for (int nt = 0; nt < 2; nt++) {
                    int nl1 = nw0 + wn + nt * 16 + l15;
                    int nl2 = nl1 + 32;
                    float x1 = acc[mt][nt][r] + bias[nl1];
                    float x2 = acc[mt][nt + 2][r] + bias[nl2];
                    float ang = (float)s * inv[nt];
                    float sn, cs;
                    __sincosf(ang, &sn, &cs);
                    int hh = nl1 >> 6, d = nl1 & 63;
                    size_t base = ((size_t)(bb * 16 + hh) * 2048 + s) * 64;
                    outp[base + d]      = (bf16)(x1 * cs - x2 * sn);
                    outp[base + d + 32] = (bf16)(x2 * cs + x1 * sn);
                }
            }
        }
    } else {
        #pragma unroll
        for (int mt = 0; mt < 4; mt++) {
            int mbase = m0 + wm + mt * 16 + quad * 4;
            int bb = mbase >> 11, s0 = mbase & 2047;
            #pragma unroll
            for (int nt = 0; nt < 4; nt++) {
                int nl = nw0 + wn + nt * 16 + l15;
                int hh = nl >> 6, d = nl & 63;
                bf16x4 pk;
                #pragma unroll
                for (int r = 0; r < 4; r++) pk[r] = (bf16)(acc[mt][nt][r] + bias[nl]);
                *(bf16x4*)&vt_ws[((size_t)(bb * 16 + hh) * 64 + d) * 2048 + s0] = pk;
            }
        }
    }
}

__global__ __launch_bounds__(256) void gemm_out_f32w(
    const bf16* __restrict__ A, const float* __restrict__ W,
    const float* __restrict__ bias, float* __restrict__ out)
{
    int m0 = blockIdx.x * 128;
    int n0 = blockIdx.y * 128;

    __shared__ bf16 As[128][72];
    __shared__ bf16 Bs[128][72];

    int tid = threadIdx.x;
    int lane = tid & 63, w = tid >> 6;
    int l15 = lane & 15, quad = lane >> 4;
    int wm = (w >> 1) * 64, wn = (w & 1) * 64;
    int sr = tid >> 1;
    int sk = (tid & 1) * 32;

    floatx4 acc[4][4];
    #pragma unroll
    for (int i = 0; i < 4; i++)
        #pragma unroll
        for (int j = 0; j < 4; j++) acc[i][j] = (floatx4){0.f, 0.f, 0.f, 0.f};

    for (int k0 = 0; k0 < 1024; k0 += 64) {
        __syncthreads();
        const bf16* ap = &A[(size_t)(m0 + sr) * 1024 + k0 + sk];
        bf16x8 a0 = *(const bf16x8*)(ap);
        bf16x8 a1 = *(const bf16x8*)(ap + 8);
        bf16x8 a2 = *(const bf16x8*)(ap + 16);
        bf16x8 a3 = *(const bf16x8*)(ap + 24);
        const float* wp = &W[(size_t)(n0 + sr) * 1024 + k0 + sk];
        bf16x8 bv_[4];
        #pragma unroll
        for (int c = 0; c < 4; c++) {
            float4 f0 = *(const float4*)(wp + c * 8);
            float4 f1 = *(const float4*)(wp + c * 8 + 4);
            bf16x8 t;
            t[0] = (bf16)f0.x; t[1] = (bf16)f0.y; t[2] = (bf16)f0.z; t[3] = (bf16)f0.w;
            t[4] = (bf16)f1.x; t[5] = (bf16)f1.y; t[6] = (bf16)f1.z; t[7] = (bf16)f1.w;
            bv_[c] = t;
        }
        *(bf16x8*)&As[sr][sk + 0]  = a0;
        *(bf16x8*)&As[sr][sk + 8]  = a1;
        *(bf16x8*)&As[sr][sk + 16] = a2;
        *(bf16x8*)&As[sr][sk + 24] = a3;
        #pragma unroll
        for (int c = 0; c < 4; c++) *(bf16x8*)&Bs[sr][sk + c * 8] = bv_[c];
        __syncthreads();
        #pragma unroll
        for (int kk = 0; kk < 64; kk += 32) {
            bf16x8 af[4], bfr[4];
            #pragma unroll
            for (int mt = 0; mt < 4; mt++)
                af[mt] = *(const bf16x8*)&As[wm + mt * 16 + l15][kk + quad * 8];
            #pragma unroll
            for (int nt = 0; nt < 4; nt++)
                bfr[nt] = *(const bf16x8*)&Bs[wn + nt * 16 + l15][kk + quad * 8];
            #pragma unroll
            for (int mt = 0; mt < 4; mt++)
                #pragma unroll
                for (int nt = 0; nt < 4; nt++)
                    acc[mt][nt] = MFMA16(af[mt], bfr[nt], acc[mt][nt]);
        }
    }

    #pragma unroll
    for (int mt = 0; mt < 4; mt++) {
        #pragma unroll
        for (int r = 0; r < 4; r++) {
            int m = m0 + wm + mt * 16 + quad * 4 + r;
            #pragma unroll
            for (int nt = 0; nt < 4; nt++) {
                int nl = n0 + wn + nt * 16 + l15;
                out[(size_t)m * 1024 + nl] = acc[mt][nt][r] + bias[nl];
            }
        }
    }
}

// ---------------------------------------------------------------------------
// MFMA flash attention V13 (verified best, round 13): KVBLK=128, qt-pairing,
// counted-vmcnt ping-pong, fixed-max softmax + ones-MFMA l, chunk-XOR
// swizzles (K 3-bit, V/Ps 4-bit), XCD pinning, unroll-2 static buffers.
// LDS: Ks[2][128][64] 32KB + Vt[2][64][128] 32KB + Ps[4][16][128] 16KB
// = 81920 B -> 2 blocks/CU.  (Unchanged.)
// ---------------------------------------------------------------------------
__global__ __launch_bounds__(256, 2) void attn_kernel(
    const bf16* __restrict__ q_ws, const bf16* __restrict__ k_ws,
    const bf16* __restrict__ vt_ws, bf16* __restrict__ o_ws)
{
    __shared__ bf16 Ks[2][128][64];   // [buf][key][d], chunk-swizzled (3-bit)
    __shared__ bf16 Vt[2][64][128];   // [buf][d][key], chunk-swizzled (4-bit)
    __shared__ bf16 Ps[4][16][128];   // per-wave P [q][key], 4-bit XOR swizzle

    int tid = threadIdx.x;
    int w = tid >> 6, lane = tid & 63;
    int l15 = lane & 15, quad = lane >> 4;

    int bid = blockIdx.x;            // 0..511
    int g = bid & 31;                // bh; bid%8==g%8 -> same XCD per bh
    int x = bid >> 5;                // 0..15
    int bb = g >> 4, h = g & 15;
    const bf16* qp = q_ws + (size_t)g * 2048 * 64;
    const bf16* kp = k_ws + (size_t)g * 2048 * 64;
    const bf16* vp = vt_ws + (size_t)g * 64 * 2048;

    // staging maps: wave w stages 4 segments (of 16) for K and for V.
    // One segment = 64 lanes x 16B = 512 bf16.
    int kr[4], kc[4], vr[4], vc[4];
    #pragma unroll
    for (int s = 0; s < 4; s++) {
        int u = (w * 4 + s) * 64 + lane;
        kr[s] = u >> 3; kc[s] = (u & 7) ^ (kr[s] & 7);
        vr[s] = u >> 4; vc[s] = (u & 15) ^ (vr[s] & 15);
    }
    int od0 = (w * 4) * 512;         // bf16 offset of wave's first segment

    const float SCL = 0.125f * 1.4426950408889634f;   // (1/sqrt(HD))*log2(e)
    const float MFIX = 20.0f;        // fixed exp2-domain shift (folded in C-init)
    int lx7 = l15 & 7;               // K-read swizzle key (row&7 == l15&7)

    bf16x8 ones8;
    #pragma unroll
    for (int i = 0; i < 8; i++) ones8[i] = (bf16)1.0f;

    #pragma unroll 1
    for (int pass = 0; pass < 2; ++pass) {
        int qt = pass ? (31 - x) : x;
        int qrow = qt * 64 + w * 16;
        int nkt = (qt + 2) >> 1;     // 128-key tiles covering keys 0..qt*64+63

        // Q B-frags resident, pre-scaled
        bf16x8 qf0 = scale8(*(const bf16x8*)&qp[(size_t)(qrow + l15) * 64 + quad * 8], SCL);
        bf16x8 qf1 = scale8(*(const bf16x8*)&qp[(size_t)(qrow + l15) * 64 + 32 + quad * 8], SCL);

        floatx4 lacc = (floatx4){0.f, 0.f, 0.f, 0.f};   // ones-MFMA l accum
        floatx4 acc[4];
        #pragma unroll
        for (int nt = 0; nt < 4; nt++) acc[nt] = (floatx4){0.f, 0.f, 0.f, 0.f};

        // running stage-source pointers (advance per 128-key tile:
        // K +8192 elems; V +128 key-cols)
        const bf16* kst[4];
        const bf16* vst[4];
        #pragma unroll
        for (int s = 0; s < 4; s++) {
            kst[s] = kp + (size_t)kr[s] * 64 + kc[s] * 8;
            vst[s] = vp + (size_t)vr[s] * 2048 + vc[s] * 8;
        }

        // prologue: stage kt=0 into buf 0.
        #pragma unroll
        for (int s = 0; s < 4; s++) {
            load_lds16(kst[s], &Ks[0][0][0] + od0 + s * 512);
            load_lds16(vst[s], &Vt[0][0][0] + od0 + s * 512);
            kst[s] += 8192; vst[s] += 128;
        }

        #pragma unroll 2
        for (int kt = 0; kt < nkt; kt++) {
            int buf = kt & 1;        // compile-time per unrolled copy
            if (kt + 1 < nkt) {
                #pragma unroll
                for (int s = 0; s < 4; s++) {
                    load_lds16(kst[s], &Ks[buf ^ 1][0][0] + od0 + s * 512);
                    load_lds16(vst[s], &Vt[buf ^ 1][0][0] + od0 + s * 512);
                    kst[s] += 8192; vst[s] += 128;
                }
                WAITV8_BAR();
            } else {
                WAITV0_BAR();
            }

            int kt0 = kt * 128;

            // S^T = K * Q^T : 8 key-blocks of 16, per lane 4 keys x 1 query.
            floatx4 st[8];
            __builtin_amdgcn_s_setprio(1);
            #pragma unroll
            for (int kb = 0; kb < 8; kb++) {
                int row = kb * 16 + l15;
                bf16x8 a0 = *(const bf16x8*)&Ks[buf][row][(quad ^ lx7) * 8];
                bf16x8 a1 = *(const bf16x8*)&Ks[buf][row][((quad + 4) ^ lx7) * 8];
                floatx4 z = {-MFIX, -MFIX, -MFIX, -MFIX};
                z = MFMA16(a0, qf0, z);
                z = MFMA16(a1, qf1, z);
                st[kb] = z;
            }
            __builtin_amdgcn_s_setprio(0);
            if (kt0 + 127 > qrow) {  // tile reaches past the diagonal: mask
                int q = qrow + l15;
                #pragma unroll
                for (int kb = 0; kb < 8; kb++)
                    #pragma unroll
                    for (int rr = 0; rr < 4; rr++) {
                        int key = kt0 + kb * 16 + quad * 4 + rr;
                        if (key > q) st[kb][rr] = -1e30f;
                    }
            }

            // fixed-max softmax; Ps write at 4-bit chunk-XOR swizzled column
            #pragma unroll
            for (int kb = 0; kb < 8; kb++) {
                bf16x4 pk;
                #pragma unroll
                for (int rr = 0; rr < 4; rr++)
                    pk[rr] = (bf16)exp2f(st[kb][rr]);
                int ch = kb * 2 + (quad >> 1);
                *(bf16x4*)&Ps[w][l15][((ch ^ l15) << 3) + ((quad & 1) << 2)] = pk;
            }

            // O^T += V^T * P^T over 4 key-slices of 32; l via ones-MFMA.
            bf16x8 pb[4];
            #pragma unroll
            for (int ks = 0; ks < 4; ks++)
                pb[ks] = *(const bf16x8*)&Ps[w][l15][((ks * 4 + quad) ^ l15) << 3];
            __builtin_amdgcn_s_setprio(1);
            #pragma unroll
            for (int nt = 0; nt < 4; nt++) {
                int row = nt * 16 + l15;
                #pragma unroll
                for (int ks = 0; ks < 4; ks++) {
                    bf16x8 v = *(const bf16x8*)&Vt[buf][row][((ks * 4 + quad) ^ l15) * 8];
                    acc[nt] = MFMA16(v, pb[ks], acc[nt]);
                }
            }
            #pragma unroll
            for (int ks = 0; ks < 4; ks++)
                lacc = MFMA16(ones8, pb[ks], lacc);
            __builtin_amdgcn_s_setprio(0);

            TRAIL_BAR();
        }

        // lacc rows are all the per-query (l15) sum: no cross-lane reduce.
        float inv = 1.f / lacc[0];
        int s = qrow + l15;
        #pragma unroll
        for (int nt = 0; nt < 4; nt++) {
            bf16x4 pk;
            #pragma unroll
            for (int rr = 0; rr < 4; rr++) pk[rr] = (bf16)(acc[nt][rr] * inv);
            *(bf16x4*)&o_ws[((size_t)(bb * 2048 + s)) * 1024 + h * 64 + nt * 16 + quad * 4] = pk;
        }
    }
}

// ---------------------------------------------------------------------------
extern "C" void kernel_launch(void* const* d_in, const int* in_sizes, int n_in,
                              void* d_out, int out_size, void* d_ws, size_t ws_size,
                              hipStream_t stream) {
    const float* x  = (const float*)d_in[0];
    const float* Wq = (const float*)d_in[1];
    const float* bq = (const float*)d_in[2];
    const float* Wk = (const float*)d_in[3];
    const float* bk = (const float*)d_in[4];
    const float* Wv = (const float*)d_in[5];
    const float* bv = (const float*)d_in[6];
    const float* Wo = (const float*)d_in[7];
    const float* bo = (const float*)d_in[8];
    float* out = (float*)d_out;

    const size_t NELEM = (size_t)2 * 2048 * 1024;   // 4,194,304
    const size_t WELEM = (size_t)1024 * 1024;
    bf16* xb    = (bf16*)d_ws;          // 8MB; reused as o_ws after qkv
    bf16* q_ws  = xb + NELEM;
    bf16* k_ws  = q_ws + NELEM;
    bf16* vt_ws = k_ws + NELEM;         // (B,NH,HD,S)
    bf16* o_ws  = xb;
    bf16* wqb   = vt_ws + NELEM;        // +2MB each
    bf16* wkb   = wqb + WELEM;
    bf16* wvb   = wkb + WELEM;
    bf16* wob   = wvb + WELEM;          // ends at 40MB

    bool fast = ws_size >= (size_t)40 * 1024 * 1024;   // constant across calls

    if (fast) {
        cvt_all_kernel<<<8192, 256, 0, stream>>>(x, Wq, Wk, Wv, Wo,
                                                 xb, wqb, wkb, wvb, wob);
        gemm_qkv_fast<<<dim3(32, 24), 256, 0, stream>>>(
            xb, wqb, wkb, wvb, bq, bk, bv, q_ws, k_ws, vt_ws);
        attn_kernel<<<512, 256, 0, stream>>>(q_ws, k_ws, vt_ws, o_ws);
        gemm_out_fast<<<dim3(32, 8), 512, 0, stream>>>(o_ws, wob, bo, out);
    } else {
        cvt_kernel<<<4096, 256, 0, stream>>>(x, xb);
        gemm_qkv_f32w<<<dim3(32, 24), 256, 0, stream>>>(
            xb, Wq, Wk, Wv, bq, bk, bv, q_ws, k_ws, vt_ws);
        attn_kernel<<<512, 256, 0, stream>>>(q_ws, k_ws, vt_ws, o_ws);
        gemm_out_f32w<<<dim3(32, 8), 256, 0, stream>>>(o_ws, Wo, bo, out);
    }
}

// Round 18
// 186.064 us; speedup vs baseline: 1.0623x; 1.0144x over previous
//
#include <hip/hip_runtime.h>

// B=2, S=2048, H=1024, NH=16, HD=64. f32 in/out; bf16 intermediates + MFMA.
// MFMA 16x16x32 bf16 layouts (m89/m91):
//   A: lane holds A[m=lane&15][k=quad*8+j]   B: B[k=quad*8+j][n=lane&15]
//   C/D: lane reg r -> row=quad*4+r, col=lane&15
typedef __bf16 bf16;
typedef __bf16 bf16x4 __attribute__((ext_vector_type(4)));
typedef __bf16 bf16x8 __attribute__((ext_vector_type(8)));
typedef float floatx4 __attribute__((ext_vector_type(4)));

#define MFMA16(a, b, c) __builtin_amdgcn_mfma_f32_16x16x32_bf16(a, b, c, 0, 0, 0)

__device__ __forceinline__ void load_lds16(const void* g, void* l) {
    // async global->LDS DMA, 16B/lane; dest = wave-uniform base + lane*16
    __builtin_amdgcn_global_load_lds(
        (const __attribute__((address_space(1))) unsigned int*)g,
        (__attribute__((address_space(3))) unsigned int*)l, 16, 0, 0);
}

__device__ __forceinline__ bf16x8 scale8(bf16x8 a, float s) {
    bf16x8 o;
    #pragma unroll
    for (int i = 0; i < 8; i++) o[i] = (bf16)((float)a[i] * s);
    return o;
}

// counted-vmcnt barrier pair (T3+T4): loads stay in flight across barriers.
#define WAITV8_BAR()  do { asm volatile("s_waitcnt vmcnt(8)" ::: "memory"); \
                           __builtin_amdgcn_s_barrier();                    \
                           __builtin_amdgcn_sched_barrier(0); } while (0)
#define WAITV4_BAR()  do { asm volatile("s_waitcnt vmcnt(4)" ::: "memory"); \
                           __builtin_amdgcn_s_barrier();                    \
                           __builtin_amdgcn_sched_barrier(0); } while (0)
#define WAITV2_BAR()  do { asm volatile("s_waitcnt vmcnt(2)" ::: "memory"); \
                           __builtin_amdgcn_s_barrier();                    \
                           __builtin_amdgcn_sched_barrier(0); } while (0)
#define WAITV0_BAR()  do { asm volatile("s_waitcnt vmcnt(0)" ::: "memory"); \
                           __builtin_amdgcn_s_barrier();                    \
                           __builtin_amdgcn_sched_barrier(0); } while (0)
#define TRAIL_BAR()   do { __builtin_amdgcn_sched_barrier(0);               \
                           asm volatile("s_waitcnt lgkmcnt(0)" ::: "memory"); \
                           __builtin_amdgcn_s_barrier(); } while (0)

// ---------------------------------------------------------------------------
// cvt: x (4096 blk), Wq/Wk/Wv/Wo (1024 blk each) f32 -> bf16
// ---------------------------------------------------------------------------
__global__ __launch_bounds__(256) void cvt_all_kernel(
    const float* __restrict__ x, const float* __restrict__ wq,
    const float* __restrict__ wk, const float* __restrict__ wv,
    const float* __restrict__ wo,
    bf16* __restrict__ xb, bf16* __restrict__ wqb, bf16* __restrict__ wkb,
    bf16* __restrict__ wvb, bf16* __restrict__ wob)
{
    int bid = blockIdx.x;
    const float* src; bf16* dst; int off;
    if (bid < 4096)      { src = x;  dst = xb;  off = bid; }
    else if (bid < 5120) { src = wq; dst = wqb; off = bid - 4096; }
    else if (bid < 6144) { src = wk; dst = wkb; off = bid - 5120; }
    else if (bid < 7168) { src = wv; dst = wvb; off = bid - 6144; }
    else                 { src = wo; dst = wob; off = bid - 7168; }
    int idx = (off * 256 + threadIdx.x) * 4;
    float4 v = *(const float4*)&src[idx];
    bf16x4 o;
    o[0] = (bf16)v.x; o[1] = (bf16)v.y; o[2] = (bf16)v.z; o[3] = (bf16)v.w;
    *(bf16x4*)&dst[idx] = o;
}

__global__ __launch_bounds__(256) void cvt_kernel(const float* __restrict__ x,
                                                  bf16* __restrict__ xb) {
    int idx = (blockIdx.x * 256 + threadIdx.x) * 4;
    float4 v = *(const float4*)&x[idx];
    bf16x4 o;
    o[0] = (bf16)v.x; o[1] = (bf16)v.y; o[2] = (bf16)v.z; o[3] = (bf16)v.w;
    *(bf16x4*)&xb[idx] = o;
}

// ===========================================================================
// FAST qkv GEMM: 2-phase BK=32 ping-pong with COUNTED vmcnt (T3+T4) + T5.
// (round-13 exact — verified fast)
// ===========================================================================

#define PREP_STAGE()                                                          \
    int u0 = w * 128 + lane;                                                  \
    int u1 = u0 + 64;                                                         \
    int r0_ = u0 >> 2, c0_ = ((u0 & 3) ^ ((r0_ >> 1) & 3)) * 8;               \
    int r1_ = u1 >> 2, c1_ = ((u1 & 3) ^ ((r1_ >> 1) & 3)) * 8;               \
    int du0 = w * 1024;                                                       \
    int du1 = du0 + 512;

#define STAGE_PF(Asrc, Bsrc, arow, brow, sbuf, kk0)                           \
    do {                                                                      \
        load_lds16(&Asrc[(size_t)((arow) + r0_) * 1024 + (kk0) + c0_],        \
                   &As[sbuf][0][0] + du0);                                    \
        load_lds16(&Asrc[(size_t)((arow) + r1_) * 1024 + (kk0) + c1_],        \
                   &As[sbuf][0][0] + du1);                                    \
        load_lds16(&Bsrc[(size_t)((brow) + r0_) * 1024 + (kk0) + c0_],        \
                   &Bs[sbuf][0][0] + du0);                                    \
        load_lds16(&Bsrc[(size_t)((brow) + r1_) * 1024 + (kk0) + c1_],        \
                   &Bs[sbuf][0][0] + du1);                                    \
    } while (0)

#define GEMM_CORE(Asrc, Bsrc, arow, brow)                                     \
    PREP_STAGE()                                                              \
    STAGE_PF(Asrc, Bsrc, arow, brow, 0, 0);                                   \
    _Pragma("unroll 2")                                                       \
    for (int s = 0; s < 32; s++) {                                            \
        int sb = s & 1;                                                       \
        if (s + 1 < 32) {                                                     \
            STAGE_PF(Asrc, Bsrc, arow, brow, sb ^ 1, (s + 1) * 32);           \
            WAITV4_BAR();                                                     \
        } else {                                                              \
            WAITV0_BAR();                                                     \
        }                                                                     \
        bf16x8 af[4], bfr[4];                                                 \
        _Pragma("unroll")                                                     \
        for (int mt = 0; mt < 4; mt++) {                                      \
            int row = wm + mt * 16 + l15;                                     \
            af[mt] = *(const bf16x8*)&As[sb][row][(quad ^ ((row >> 1) & 3)) * 8]; \
        }                                                                     \
        _Pragma("unroll")                                                     \
        for (int nt = 0; nt < 4; nt++) {                                      \
            int row = wn + nt * 16 + l15;                                     \
            bfr[nt] = *(const bf16x8*)&Bs[sb][row][(quad ^ ((row >> 1) & 3)) * 8]; \
        }                                                                     \
        __builtin_amdgcn_s_setprio(1);                                        \
        _Pragma("unroll")                                                     \
        for (int mt = 0; mt < 4; mt++)                                        \
            _Pragma("unroll")                                                 \
            for (int nt = 0; nt < 4; nt++)                                    \
                acc[mt][nt] = MFMA16(af[mt], bfr[nt], acc[mt][nt]);           \
        __builtin_amdgcn_s_setprio(0);                                        \
        TRAIL_BAR();                                                          \
    }

// ---------------------------------------------------------------------------
// QKV projection + bias + fused RoPE (q,k) + transposed V store.
// q_ws,k_ws: (B,NH,S,HD); vt_ws: (B,NH,HD,S). All-bf16 inputs.
// ---------------------------------------------------------------------------
__global__ __launch_bounds__(256) void gemm_qkv_fast(
    const bf16* __restrict__ xb,
    const bf16* __restrict__ Wq, const bf16* __restrict__ Wk,
    const bf16* __restrict__ Wv,
    const float* __restrict__ bq, const float* __restrict__ bk,
    const float* __restrict__ bv,
    bf16* __restrict__ q_ws, bf16* __restrict__ k_ws, bf16* __restrict__ vt_ws)
{
    int m0 = blockIdx.x * 128;
    int n0 = blockIdx.y * 128;
    int sec = n0 >> 10;
    int nw0 = n0 & 1023;
    const bf16* W     = (sec == 0) ? Wq : (sec == 1) ? Wk : Wv;
    const float* bias = (sec == 0) ? bq : (sec == 1) ? bk : bv;

    __shared__ bf16 As[2][128][32];
    __shared__ bf16 Bs[2][128][32];

    int tid = threadIdx.x;
    int lane = tid & 63, w = tid >> 6;
    int l15 = lane & 15, quad = lane >> 4;
    int wm = (w >> 1) * 64, wn = (w & 1) * 64;

    floatx4 acc[4][4];
    #pragma unroll
    for (int i = 0; i < 4; i++)
        #pragma unroll
        for (int j = 0; j < 4; j++) acc[i][j] = (floatx4){0.f, 0.f, 0.f, 0.f};

    GEMM_CORE(xb, W, m0, nw0)

    if (sec < 2) {
        bf16* outp = (sec == 0) ? q_ws : k_ws;
        float inv[2];
        inv[0] = __expf(-(float)l15 * (9.210340371976184f / 32.0f));
        inv[1] = __expf(-(float)(16 + l15) * (9.210340371976184f / 32.0f));
        #pragma unroll
        for (int mt = 0; mt < 4; mt++) {
            #pragma unroll
            for (int r = 0; r < 4; r++) {
                int m = m0 + wm + mt * 16 + quad * 4 + r;
                int bb = m >> 11, s = m & 2047;
                #pragma unroll
                for (int nt = 0; nt < 2; nt++) {
                    int nl1 = nw0 + wn + nt * 16 + l15;
                    int nl2 = nl1 + 32;
                    float x1 = acc[mt][nt][r] + bias[nl1];
                    float x2 = acc[mt][nt + 2][r] + bias[nl2];
                    float ang = (float)s * inv[nt];
                    float sn, cs;
                    __sincosf(ang, &sn, &cs);
                    int hh = nl1 >> 6, d = nl1 & 63;
                    size_t base = ((size_t)(bb * 16 + hh) * 2048 + s) * 64;
                    outp[base + d]      = (bf16)(x1 * cs - x2 * sn);
                    outp[base + d + 32] = (bf16)(x2 * cs + x1 * sn);
                }
            }
        }
    } else {
        #pragma unroll
        for (int mt = 0; mt < 4; mt++) {
            int mbase = m0 + wm + mt * 16 + quad * 4;
            int bb = mbase >> 11, s0 = mbase & 2047;
            #pragma unroll
            for (int nt = 0; nt < 4; nt++) {
                int nl = nw0 + wn + nt * 16 + l15;
                int hh = nl >> 6, d = nl & 63;
                bf16x4 pk;
                #pragma unroll
                for (int r = 0; r < 4; r++) pk[r] = (bf16)(acc[mt][nt][r] + bias[nl]);
                *(bf16x4*)&vt_ws[((size_t)(bb * 16 + hh) * 64 + d) * 2048 + s0] = pk;
            }
        }
    }
}

// ---------------------------------------------------------------------------
// Output projection V3 (round-17 verified): 512 threads / 8 waves on the
// 128x128 tile; each wave stages TWO segments of its half (A for w<4, B for
// w>=4); counted vmcnt(2) ping-pong; each wave computes 32x64.
// ---------------------------------------------------------------------------
__global__ __launch_bounds__(512) void gemm_out_fast(
    const bf16* __restrict__ A, const bf16* __restrict__ W,
    const float* __restrict__ bias, float* __restrict__ out)
{
    int m0 = blockIdx.x * 128;
    int n0 = blockIdx.y * 128;

    __shared__ bf16 As[2][128][32];
    __shared__ bf16 Bs[2][128][32];

    int tid = threadIdx.x;
    int lane = tid & 63, w = tid >> 6;      // w in 0..7
    int l15 = lane & 15, quad = lane >> 4;
    int wm = (w >> 1) * 32, wn = (w & 1) * 64;

    // staging: wave w stages segments {2(w&3), 2(w&3)+1} of (w<4 ? A : B).
    int u0 = (w & 3) * 128 + lane;          // 16B-unit 0..511 within half
    int u1 = u0 + 64;
    int sr0 = u0 >> 2, sc0 = ((u0 & 3) ^ ((sr0 >> 1) & 3)) * 8;
    int sr1 = u1 >> 2, sc1 = ((u1 & 3) ^ ((sr1 >> 1) & 3)) * 8;
    int du0 = (w & 3) * 1024;               // bf16 dest offsets
    int du1 = du0 + 512;
    const bf16* base = (w < 4) ? &A[(size_t)m0 * 1024] : &W[(size_t)n0 * 1024];
    const bf16* src0 = base + (size_t)sr0 * 1024 + sc0;
    const bf16* src1 = base + (size_t)sr1 * 1024 + sc1;

    floatx4 acc[2][4];
    #pragma unroll
    for (int i = 0; i < 2; i++)
        #pragma unroll
        for (int j = 0; j < 4; j++) acc[i][j] = (floatx4){0.f, 0.f, 0.f, 0.f};

    // prologue: stage tile 0 into buf 0
    {
        bf16* d0 = ((w < 4) ? &As[0][0][0] : &Bs[0][0][0]) + du0;
        bf16* d1 = ((w < 4) ? &As[0][0][0] : &Bs[0][0][0]) + du1;
        load_lds16(src0, d0);
        load_lds16(src1, d1);
    }

    #pragma unroll 2
    for (int s = 0; s < 32; s++) {
        int sb = s & 1;
        if (s + 1 < 32) {
            bf16* d0 = ((w < 4) ? &As[sb ^ 1][0][0] : &Bs[sb ^ 1][0][0]) + du0;
            bf16* d1 = ((w < 4) ? &As[sb ^ 1][0][0] : &Bs[sb ^ 1][0][0]) + du1;
            load_lds16(src0 + (s + 1) * 32, d0);
            load_lds16(src1 + (s + 1) * 32, d1);
            WAITV2_BAR();
        } else {
            WAITV0_BAR();
        }

        bf16x8 af[2], bfr[4];
        #pragma unroll
        for (int mt = 0; mt < 2; mt++) {
            int row = wm + mt * 16 + l15;
            af[mt] = *(const bf16x8*)&As[sb][row][(quad ^ ((row >> 1) & 3)) * 8];
        }
        #pragma unroll
        for (int nt = 0; nt < 4; nt++) {
            int row = wn + nt * 16 + l15;
            bfr[nt] = *(const bf16x8*)&Bs[sb][row][(quad ^ ((row >> 1) & 3)) * 8];
        }
        __builtin_amdgcn_s_setprio(1);
        #pragma unroll
        for (int mt = 0; mt < 2; mt++)
            #pragma unroll
            for (int nt = 0; nt < 4; nt++)
                acc[mt][nt] = MFMA16(af[mt], bfr[nt], acc[mt][nt]);
        __builtin_amdgcn_s_setprio(0);
        TRAIL_BAR();
    }

    #pragma unroll
    for (int mt = 0; mt < 2; mt++) {
        #pragma unroll
        for (int r = 0; r < 4; r++) {
            int m = m0 + wm + mt * 16 + quad * 4 + r;
            #pragma unroll
            for (int nt = 0; nt < 4; nt++) {
                int nl = n0 + wn + nt * 16 + l15;
                out[(size_t)m * 1024 + nl] = acc[mt][nt][r] + bias[nl];
            }
        }
    }
}

// ===========================================================================
// FALLBACK GEMMs (f32 W staged with in-flight cvt) — used if ws too small
// ===========================================================================
__global__ __launch_bounds__(256) void gemm_qkv_f32w(
    const bf16* __restrict__ xb,
    const float* __restrict__ Wq, const float* __restrict__ Wk,
    const float* __restrict__ Wv,
    const float* __restrict__ bq, const float* __restrict__ bk,
    const float* __restrict__ bv,
    bf16* __restrict__ q_ws, bf16* __restrict__ k_ws, bf16* __restrict__ vt_ws)
{
    int m0 = blockIdx.x * 128;
    int n0 = blockIdx.y * 128;
    int sec = n0 >> 10;
    int nw0 = n0 & 1023;
    const float* W    = (sec == 0) ? Wq : (sec == 1) ? Wk : Wv;
    const float* bias = (sec == 0) ? bq : (sec == 1) ? bk : bv;

    __shared__ bf16 As[128][72];
    __shared__ bf16 Bs[128][72];

    int tid = threadIdx.x;
    int lane = tid & 63, w = tid >> 6;
    int l15 = lane & 15, quad = lane >> 4;
    int wm = (w >> 1) * 64, wn = (w & 1) * 64;
    int sr = tid >> 1;
    int sk = (tid & 1) * 32;

    floatx4 acc[4][4];
    #pragma unroll
    for (int i = 0; i < 4; i++)
        #pragma unroll
        for (int j = 0; j < 4; j++) acc[i][j] = (floatx4){0.f, 0.f, 0.f, 0.f};

    for (int k0 = 0; k0 < 1024; k0 += 64) {
        __syncthreads();
        const bf16* ap = &xb[(size_t)(m0 + sr) * 1024 + k0 + sk];
        bf16x8 a0 = *(const bf16x8*)(ap);
        bf16x8 a1 = *(const bf16x8*)(ap + 8);
        bf16x8 a2 = *(const bf16x8*)(ap + 16);
        bf16x8 a3 = *(const bf16x8*)(ap + 24);
        const float* wp = &W[(size_t)(nw0 + sr) * 1024 + k0 + sk];
        bf16x8 bv_[4];
        #pragma unroll
        for (int c = 0; c < 4; c++) {
            float4 f0 = *(const float4*)(wp + c * 8);
            float4 f1 = *(const float4*)(wp + c * 8 + 4);
            bf16x8 t;
            t[0] = (bf16)f0.x; t[1] = (bf16)f0.y; t[2] = (bf16)f0.z; t[3] = (bf16)f0.w;
            t[4] = (bf16)f1.x; t[5] = (bf16)f1.y; t[6] = (bf16)f1.z; t[7] = (bf16)f1.w;
            bv_[c] = t;
        }
        *(bf16x8*)&As[sr][sk + 0]  = a0;
        *(bf16x8*)&As[sr][sk + 8]  = a1;
        *(bf16x8*)&As[sr][sk + 16] = a2;
        *(bf16x8*)&As[sr][sk + 24] = a3;
        #pragma unroll
        for (int c = 0; c < 4; c++) *(bf16x8*)&Bs[sr][sk + c * 8] = bv_[c];
        __syncthreads();
        #pragma unroll
        for (int kk = 0; kk < 64; kk += 32) {
            bf16x8 af[4], bfr[4];
            #pragma unroll
            for (int mt = 0; mt < 4; mt++)
                af[mt] = *(const bf16x8*)&As[wm + mt * 16 + l15][kk + quad * 8];
            #pragma unroll
            for (int nt = 0; nt < 4; nt++)
                bfr[nt] = *(const bf16x8*)&Bs[wn + nt * 16 + l15][kk + quad * 8];
            #pragma unroll
            for (int mt = 0; mt < 4; mt++)
                #pragma unroll
                for (int nt = 0; nt < 4; nt++)
                    acc[mt][nt] = MFMA16(af[mt], bfr[nt], acc[mt][nt]);
        }
    }

    if (sec < 2) {
        bf16* outp = (sec == 0) ? q_ws : k_ws;
        float inv[2];
        inv[0] = __expf(-(float)l15 * (9.210340371976184f / 32.0f));
        inv[1] = __expf(-(float)(16 + l15) * (9.210340371976184f / 32.0f));
        #pragma unroll
        for (int mt = 0; mt < 4; mt++) {
            #pragma unroll
            for (int r = 0; r < 4; r++) {
                int m = m0 + wm + mt * 16 + quad * 4 + r;
                int bb = m >> 11, s = m & 2047;
                #pragma unroll
                for (int nt = 0; nt < 2; nt++) {
                    int nl1 = nw0 + wn + nt * 16 + l15;
                    int nl2 = nl1 + 32;
                    float x1 = acc[mt][nt][r] + bias[nl1];
                    float x2 = acc[mt][nt + 2][r] + bias[nl2];
                    float ang = (float)s * inv[nt];
                    float sn, cs;
                    __sincosf(ang, &sn, &cs);
                    int hh = nl1 >> 6, d = nl1 & 63;
                    size_t base = ((size_t)(bb * 16 + hh) * 2048 + s) * 64;
                    outp[base + d]      = (bf16)(x1 * cs - x2 * sn);
                    outp[base + d + 32] = (bf16)(x2 * cs + x1 * sn);
                }
            }
        }
    } else {
        #pragma unroll
        for (int mt = 0; mt < 4; mt++) {
            int mbase = m0 + wm + mt * 16 + quad * 4;
            int bb = mbase >> 11, s0 = mbase & 2047;
            #pragma unroll
            for (int nt = 0; nt < 4; nt++) {
                int nl = nw0 + wn + nt * 16 + l15;
                int hh = nl >> 6, d = nl & 63;
                bf16x4 pk;
                #pragma unroll
                for (int r = 0; r < 4; r++) pk[r] = (bf16)(acc[mt][nt][r] + bias[nl]);
                *(bf16x4*)&vt_ws[((size_t)(bb * 16 + hh) * 64 + d) * 2048 + s0] = pk;
            }
        }
    }
}

__global__ __launch_bounds__(256) void gemm_out_f32w(
    const bf16* __restrict__ A, const float* __restrict__ W,
    const float* __restrict__ bias, float* __restrict__ out)
{
    int m0 = blockIdx.x * 128;
    int n0 = blockIdx.y * 128;

    __shared__ bf16 As[128][72];
    __shared__ bf16 Bs[128][72];

    int tid = threadIdx.x;
    int lane = tid & 63, w = tid >> 6;
    int l15 = lane & 15, quad = lane >> 4;
    int wm = (w >> 1) * 64, wn = (w & 1) * 64;
    int sr = tid >> 1;
    int sk = (tid & 1) * 32;

    floatx4 acc[4][4];
    #pragma unroll
    for (int i = 0; i < 4; i++)
        #pragma unroll
        for (int j = 0; j < 4; j++) acc[i][j] = (floatx4){0.f, 0.f, 0.f, 0.f};

    for (int k0 = 0; k0 < 1024; k0 += 64) {
        __syncthreads();
        const bf16* ap = &A[(size_t)(m0 + sr) * 1024 + k0 + sk];
        bf16x8 a0 = *(const bf16x8*)(ap);
        bf16x8 a1 = *(const bf16x8*)(ap + 8);
        bf16x8 a2 = *(const bf16x8*)(ap + 16);
        bf16x8 a3 = *(const bf16x8*)(ap + 24);
        const float* wp = &W[(size_t)(n0 + sr) * 1024 + k0 + sk];
        bf16x8 bv_[4];
        #pragma unroll
        for (int c = 0; c < 4; c++) {
            float4 f0 = *(const float4*)(wp + c * 8);
            float4 f1 = *(const float4*)(wp + c * 8 + 4);
            bf16x8 t;
            t[0] = (bf16)f0.x; t[1] = (bf16)f0.y; t[2] = (bf16)f0.z; t[3] = (bf16)f0.w;
            t[4] = (bf16)f1.x; t[5] = (bf16)f1.y; t[6] = (bf16)f1.z; t[7] = (bf16)f1.w;
            bv_[c] = t;
        }
        *(bf16x8*)&As[sr][sk + 0]  = a0;
        *(bf16x8*)&As[sr][sk + 8]  = a1;
        *(bf16x8*)&As[sr][sk + 16] = a2;
        *(bf16x8*)&As[sr][sk + 24] = a3;
        #pragma unroll
        for (int c = 0; c < 4; c++) *(bf16x8*)&Bs[sr][sk + c * 8] = bv_[c];
        __syncthreads();
        #pragma unroll
        for (int kk = 0; kk < 64; kk += 32) {
            bf16x8 af[4], bfr[4];
            #pragma unroll
            for (int mt = 0; mt < 4; mt++)
                af[mt] = *(const bf16x8*)&As[wm + mt * 16 + l15][kk + quad * 8];
            #pragma unroll
            for (int nt = 0; nt < 4; nt++)
                bfr[nt] = *(const bf16x8*)&Bs[wn + nt * 16 + l15][kk + quad * 8];
            #pragma unroll
            for (int mt = 0; mt < 4; mt++)
                #pragma unroll
                for (int nt = 0; nt < 4; nt++)
                    acc[mt][nt] = MFMA16(af[mt], bfr[nt], acc[mt][nt]);
        }
    }

    #pragma unroll
    for (int mt = 0; mt < 4; mt++) {
        #pragma unroll
        for (int r = 0; r < 4; r++) {
            int m = m0 + wm + mt * 16 + quad * 4 + r;
            #pragma unroll
            for (int nt = 0; nt < 4; nt++) {
                int nl = n0 + wn + nt * 16 + l15;
                out[(size_t)m * 1024 + nl] = acc[mt][nt][r] + bias[nl];
            }
        }
    }
}

// ---------------------------------------------------------------------------
// MFMA flash attention V18: V13 + PEELED EPILOGUE with parity branch.
// With KVBLK=128 and qt-pairing, every block's EVEN-qt pass wastes the upper
// half of its final key tile (keys kt0+64..kt0+127 > q_max = qt*64+63 for all
// waves -> fully masked). V18 peels the last tile: main loop runs tiles
// 0..nkt-2 (always prefetch, full body, unroll-2 static buffers — identical
// semantics); the peeled tile runs a 4-kb/2-ks HALF body when qt is even.
// Saves ~3% of attn work (one half-tile per block pair).
// Everything else = V13 verified: counted-vmcnt ping-pong, chunk-XOR
// swizzles (K 3-bit, V/Ps 4-bit), fixed-max softmax + ones-MFMA l,
// XCD pinning, qt-pairing grid 512. LDS 81920 B -> 2 blocks/CU.
// ---------------------------------------------------------------------------

// One key-tile body. BUF: LDS buffer index; KBN: key-blocks (8 full / 4 half);
// KSN: PV key-slices (4 full / 2 half). Ps chunk mapping: half body writes
// ch 0..7 and reads chunks (ks*4+quad) in 0..7 — consistent.
#define ATTN_TILE(BUF, KBN, KSN)                                              \
    do {                                                                      \
        floatx4 st[KBN];                                                      \
        __builtin_amdgcn_s_setprio(1);                                        \
        _Pragma("unroll")                                                     \
        for (int kb = 0; kb < KBN; kb++) {                                    \
            int row = kb * 16 + l15;                                          \
            bf16x8 a0 = *(const bf16x8*)&Ks[BUF][row][(quad ^ lx7) * 8];      \
            bf16x8 a1 = *(const bf16x8*)&Ks[BUF][row][((quad + 4) ^ lx7) * 8];\
            floatx4 z = {-MFIX, -MFIX, -MFIX, -MFIX};                         \
            z = MFMA16(a0, qf0, z);                                           \
            z = MFMA16(a1, qf1, z);                                           \
            st[kb] = z;                                                       \
        }                                                                     \
        __builtin_amdgcn_s_setprio(0);                                        \
        if (kt0 + KBN * 16 - 1 > qrow) {                                      \
            int q = qrow + l15;                                               \
            _Pragma("unroll")                                                 \
            for (int kb = 0; kb < KBN; kb++)                                  \
                _Pragma("unroll")                                             \
                for (int rr = 0; rr < 4; rr++) {                              \
                    int key = kt0 + kb * 16 + quad * 4 + rr;                  \
                    if (key > q) st[kb][rr] = -1e30f;                         \
                }                                                             \
        }                                                                     \
        _Pragma("unroll")                                                     \
        for (int kb = 0; kb < KBN; kb++) {                                    \
            bf16x4 pk;                                                        \
            _Pragma("unroll")                                                 \
            for (int rr = 0; rr < 4; rr++)                                    \
                pk[rr] = (bf16)exp2f(st[kb][rr]);                             \
            int ch = kb * 2 + (quad >> 1);                                    \
            *(bf16x4*)&Ps[w][l15][((ch ^ l15) << 3) + ((quad & 1) << 2)] = pk;\
        }                                                                     \
        bf16x8 pb[KSN];                                                       \
        _Pragma("unroll")                                                     \
        for (int ks = 0; ks < KSN; ks++)                                      \
            pb[ks] = *(const bf16x8*)&Ps[w][l15][((ks * 4 + quad) ^ l15) << 3]; \
        __builtin_amdgcn_s_setprio(1);                                        \
        _Pragma("unroll")                                                     \
        for (int nt = 0; nt < 4; nt++) {                                      \
            int row = nt * 16 + l15;                                          \
            _Pragma("unroll")                                                 \
            for (int ks = 0; ks < KSN; ks++) {                                \
                bf16x8 v = *(const bf16x8*)&Vt[BUF][row][((ks * 4 + quad) ^ l15) * 8]; \
                acc[nt] = MFMA16(v, pb[ks], acc[nt]);                         \
            }                                                                 \
        }                                                                     \
        _Pragma("unroll")                                                     \
        for (int ks = 0; ks < KSN; ks++)                                      \
            lacc = MFMA16(ones8, pb[ks], lacc);                               \
        __builtin_amdgcn_s_setprio(0);                                        \
    } while (0)

__global__ __launch_bounds__(256, 2) void attn_kernel(
    const bf16* __restrict__ q_ws, const bf16* __restrict__ k_ws,
    const bf16* __restrict__ vt_ws, bf16* __restrict__ o_ws)
{
    __shared__ bf16 Ks[2][128][64];   // [buf][key][d], chunk-swizzled (3-bit)
    __shared__ bf16 Vt[2][64][128];   // [buf][d][key], chunk-swizzled (4-bit)
    __shared__ bf16 Ps[4][16][128];   // per-wave P [q][key], 4-bit XOR swizzle

    int tid = threadIdx.x;
    int w = tid >> 6, lane = tid & 63;
    int l15 = lane & 15, quad = lane >> 4;

    int bid = blockIdx.x;            // 0..511
    int g = bid & 31;                // bh; bid%8==g%8 -> same XCD per bh
    int x = bid >> 5;                // 0..15
    int bb = g >> 4, h = g & 15;
    const bf16* qp = q_ws + (size_t)g * 2048 * 64;
    const bf16* kp = k_ws + (size_t)g * 2048 * 64;
    const bf16* vp = vt_ws + (size_t)g * 64 * 2048;

    // staging maps: wave w stages 4 segments (of 16) for K and for V.
    int kr[4], kc[4], vr[4], vc[4];
    #pragma unroll
    for (int s = 0; s < 4; s++) {
        int u = (w * 4 + s) * 64 + lane;
        kr[s] = u >> 3; kc[s] = (u & 7) ^ (kr[s] & 7);
        vr[s] = u >> 4; vc[s] = (u & 15) ^ (vr[s] & 15);
    }
    int od0 = (w * 4) * 512;         // bf16 offset of wave's first segment

    const float SCL = 0.125f * 1.4426950408889634f;   // (1/sqrt(HD))*log2(e)
    const float MFIX = 20.0f;        // fixed exp2-domain shift (folded in C-init)
    int lx7 = l15 & 7;               // K-read swizzle key (row&7 == l15&7)

    bf16x8 ones8;
    #pragma unroll
    for (int i = 0; i < 8; i++) ones8[i] = (bf16)1.0f;

    #pragma unroll 1
    for (int pass = 0; pass < 2; ++pass) {
        int qt = pass ? (31 - x) : x;
        int qrow = qt * 64 + w * 16;
        int nkt = (qt + 2) >> 1;     // 128-key tiles covering keys 0..qt*64+63

        // Q B-frags resident, pre-scaled
        bf16x8 qf0 = scale8(*(const bf16x8*)&qp[(size_t)(qrow + l15) * 64 + quad * 8], SCL);
        bf16x8 qf1 = scale8(*(const bf16x8*)&qp[(size_t)(qrow + l15) * 64 + 32 + quad * 8], SCL);

        floatx4 lacc = (floatx4){0.f, 0.f, 0.f, 0.f};   // ones-MFMA l accum
        floatx4 acc[4];
        #pragma unroll
        for (int nt = 0; nt < 4; nt++) acc[nt] = (floatx4){0.f, 0.f, 0.f, 0.f};

        // running stage-source pointers (advance per 128-key tile)
        const bf16* kst[4];
        const bf16* vst[4];
        #pragma unroll
        for (int s = 0; s < 4; s++) {
            kst[s] = kp + (size_t)kr[s] * 64 + kc[s] * 8;
            vst[s] = vp + (size_t)vr[s] * 2048 + vc[s] * 8;
        }

        // prologue: stage kt=0 into buf 0.
        #pragma unroll
        for (int s = 0; s < 4; s++) {
            load_lds16(kst[s], &Ks[0][0][0] + od0 + s * 512);
            load_lds16(vst[s], &Vt[0][0][0] + od0 + s * 512);
            kst[s] += 8192; vst[s] += 128;
        }

        // main loop: all tiles that have a successor (full body + prefetch)
        #pragma unroll 2
        for (int kt = 0; kt + 1 < nkt; kt++) {
            int buf = kt & 1;        // compile-time per unrolled copy
            #pragma unroll
            for (int s = 0; s < 4; s++) {
                load_lds16(kst[s], &Ks[buf ^ 1][0][0] + od0 + s * 512);
                load_lds16(vst[s], &Vt[buf ^ 1][0][0] + od0 + s * 512);
                kst[s] += 8192; vst[s] += 128;
            }
            WAITV8_BAR();
            int kt0 = kt * 128;
            ATTN_TILE(buf, 8, 4);
            TRAIL_BAR();
        }

        // peeled final tile (no prefetch): half body when qt is even —
        // keys kt0+64.. exceed q_max = qt*64+63 for every wave.
        {
            int ebuf = (nkt - 1) & 1;
            int kt0 = (nkt - 1) * 128;
            WAITV0_BAR();
            if (qt & 1) {
                ATTN_TILE(ebuf, 8, 4);
            } else {
                ATTN_TILE(ebuf, 4, 2);
            }
            TRAIL_BAR();
        }

        // lacc rows are all the per-query (l15) sum: no cross-lane reduce.
        float inv = 1.f / lacc[0];
        int s = qrow + l15;
        #pragma unroll
        for (int nt = 0; nt < 4; nt++) {
            bf16x4 pk;
            #pragma unroll
            for (int rr = 0; rr < 4; rr++) pk[rr] = (bf16)(acc[nt][rr] * inv);
            *(bf16x4*)&o_ws[((size_t)(bb * 2048 + s)) * 1024 + h * 64 + nt * 16 + quad * 4] = pk;
        }
    }
}

// ---------------------------------------------------------------------------
extern "C" void kernel_launch(void* const* d_in, const int* in_sizes, int n_in,
                              void* d_out, int out_size, void* d_ws, size_t ws_size,
                              hipStream_t stream) {
    const float* x  = (const float*)d_in[0];
    const float* Wq = (const float*)d_in[1];
    const float* bq = (const float*)d_in[2];
    const float* Wk = (const float*)d_in[3];
    const float* bk = (const float*)d_in[4];
    const float* Wv = (const float*)d_in[5];
    const float* bv = (const float*)d_in[6];
    const float* Wo = (const float*)d_in[7];
    const float* bo = (const float*)d_in[8];
    float* out = (float*)d_out;

    const size_t NELEM = (size_t)2 * 2048 * 1024;   // 4,194,304
    const size_t WELEM = (size_t)1024 * 1024;
    bf16* xb    = (bf16*)d_ws;          // 8MB; reused as o_ws after qkv
    bf16* q_ws  = xb + NELEM;
    bf16* k_ws  = q_ws + NELEM;
    bf16* vt_ws = k_ws + NELEM;         // (B,NH,HD,S)
    bf16* o_ws  = xb;
    bf16* wqb   = vt_ws + NELEM;        // +2MB each
    bf16* wkb   = wqb + WELEM;
    bf16* wvb   = wkb + WELEM;
    bf16* wob   = wvb + WELEM;          // ends at 40MB

    bool fast = ws_size >= (size_t)40 * 1024 * 1024;   // constant across calls

    if (fast) {
        cvt_all_kernel<<<8192, 256, 0, stream>>>(x, Wq, Wk, Wv, Wo,
                                                 xb, wqb, wkb, wvb, wob);
        gemm_qkv_fast<<<dim3(32, 24), 256, 0, stream>>>(
            xb, wqb, wkb, wvb, bq, bk, bv, q_ws, k_ws, vt_ws);
        attn_kernel<<<512, 256, 0, stream>>>(q_ws, k_ws, vt_ws, o_ws);
        gemm_out_fast<<<dim3(32, 8), 512, 0, stream>>>(o_ws, wob, bo, out);
    } else {
        cvt_kernel<<<4096, 256, 0, stream>>>(x, xb);
        gemm_qkv_f32w<<<dim3(32, 24), 256, 0, stream>>>(
            xb, Wq, Wk, Wv, bq, bk, bv, q_ws, k_ws, vt_ws);
        attn_kernel<<<512, 256, 0, stream>>>(q_ws, k_ws, vt_ws, o_ws);
        gemm_out_f32w<<<dim3(32, 8), 256, 0, stream>>>(o_ws, Wo, bo, out);
    }
}